// Round 6
// baseline (171.135 us; speedup 1.0000x reference)
//
#include <hip/hip_runtime.h>
#include <math.h>

#define BB 16
#define NN 4096
#define EE 65536
#define IN_F 128
#define HH 512
#define F1 64
#define D1 512
#define D2 32768
#define EPSV 1e-5f
#define PADMAX 94208  // EE + NN*7 worst-case padded CSR

// bf16 helpers (RNE pack, cheap unpack)
__device__ __forceinline__ unsigned bfpack2(float a, float b) {
    unsigned ua = __float_as_uint(a), ub = __float_as_uint(b);
    ua += 0x7fffu + ((ua >> 16) & 1u);
    ub += 0x7fffu + ((ub >> 16) & 1u);
    return (ua >> 16) | (ub & 0xffff0000u);
}
__device__ __forceinline__ float bflo(unsigned u) { return __uint_as_float(u << 16); }
__device__ __forceinline__ float bfhi(unsigned u) { return __uint_as_float(u & 0xffff0000u); }

// ---------------- GCN support: histogram / scan / pad / CSR fill ----------------

__global__ void k_hist(const int* __restrict__ dst, int* __restrict__ cnt) {
    int i = blockIdx.x * 256 + threadIdx.x;
    if (i < EE) atomicAdd(&cnt[dst[i]], 1);
}

// prefix-sum of PADDED counts (each node's row padded to multiple of 8)
__global__ void k_scan(const int* __restrict__ cnt, int* __restrict__ row_start,
                       int* __restrict__ cursor, float* __restrict__ dis) {
    __shared__ int lds[1024];
    int tid = threadIdx.x;
    int v0 = cnt[tid * 4 + 0];
    int v1 = cnt[tid * 4 + 1];
    int v2 = cnt[tid * 4 + 2];
    int v3 = cnt[tid * 4 + 3];
    int p0 = (v0 + 7) & ~7, p1 = (v1 + 7) & ~7, p2 = (v2 + 7) & ~7, p3 = (v3 + 7) & ~7;
    int s = p0 + p1 + p2 + p3;
    lds[tid] = s;
    __syncthreads();
    for (int off = 1; off < 1024; off <<= 1) {
        int t = (tid >= off) ? lds[tid - off] : 0;
        __syncthreads();
        lds[tid] += t;
        __syncthreads();
    }
    int e = (tid > 0) ? lds[tid - 1] : 0;
    int idx = tid * 4;
    row_start[idx + 0] = e; cursor[idx + 0] = e; dis[idx + 0] = rsqrtf((float)(v0 + 1)); e += p0;
    row_start[idx + 1] = e; cursor[idx + 1] = e; dis[idx + 1] = rsqrtf((float)(v1 + 1)); e += p1;
    row_start[idx + 2] = e; cursor[idx + 2] = e; dis[idx + 2] = rsqrtf((float)(v2 + 1)); e += p2;
    row_start[idx + 3] = e; cursor[idx + 3] = e; dis[idx + 3] = rsqrtf((float)(v3 + 1)); e += p3;
    if (tid == 1023) row_start[4096] = lds[1023];
}

__global__ void k_padfill(int* __restrict__ csr) {
    int i = blockIdx.x * 256 + threadIdx.x;
    csr[i] = NN;  // sentinel -> zero block
}

__global__ void k_fill(const int* __restrict__ src, const int* __restrict__ dst,
                       int* __restrict__ cursor, int* __restrict__ csr_src) {
    int i = blockIdx.x * 256 + threadIdx.x;
    if (i < EE) {
        int d = dst[i];
        int p = atomicAdd(&cursor[d], 1);
        csr_src[p] = src[i];
    }
}

// ---------------- hws0 = bf16( dis[n] * (pos @ W0) ) ----------------
// layout [split=b>>1][n][b&1][g] bf16: per (split,node) 128 bf16 = 64 uints = 256B
// slice per split = (NN+1)*256B = 1.05 MB -> fits one XCD L2

__global__ void k_hw0(const float* __restrict__ pos, const float* __restrict__ W0,
                      const float* __restrict__ dis, unsigned* __restrict__ hws0) {
    int n = blockIdx.x;
    int tid = threadIdx.x;
    int b = tid >> 4;
    int g0 = (tid & 15) * 4;
    int split = b >> 1, b_loc = b & 1;
    unsigned* dst = hws0 + (size_t)split * ((NN + 1) * 64) + (size_t)n * 64 + b_loc * 32 + (g0 >> 1);
    if (n == NN) {
        *(uint2*)dst = make_uint2(0u, 0u);
        return;
    }
    float d = dis[n];
    const float* p = pos + b * (NN * 3) + n * 3;
    float p0 = p[0], p1 = p[1], p2 = p[2];
    float4 w0 = *(const float4*)(W0 + g0);
    float4 w1 = *(const float4*)(W0 + 64 + g0);
    float4 w2 = *(const float4*)(W0 + 128 + g0);
    float o0 = d * (p0 * w0.x + p1 * w1.x + p2 * w2.x);
    float o1 = d * (p0 * w0.y + p1 * w1.y + p2 * w2.y);
    float o2 = d * (p0 * w0.z + p1 * w1.z + p2 * w2.z);
    float o3 = d * (p0 * w0.w + p1 * w1.w + p2 * w2.w);
    uint2 pk;
    pk.x = bfpack2(o0, o1);
    pk.y = bfpack2(o2, o3);
    *(uint2*)dst = pk;
}

// ---------------- layer0: split-sliced gather + W1 matmul -> hws1 ----------------
// 1 wave per (n,split); blockIdx = n*8+split so split s pins to XCD s (round-robin).
// Indices register-held per-lane, broadcast via __shfl (no vmem dep on index path).

__global__ void k_layer0(const unsigned* __restrict__ hws0, const int* __restrict__ row_start,
                         const int* __restrict__ csr_src, const float* __restrict__ dis,
                         const float* __restrict__ bias0, const float* __restrict__ W1,
                         unsigned* __restrict__ hws1) {
    __shared__ float h0[2][64];
    int bid = blockIdx.x;
    int n = bid >> 3;
    int split = bid & 7;
    int lane = threadIdx.x;
    size_t slice = (size_t)split * ((NN + 1) * 64);
    if (n == NN) {
        hws1[slice + (size_t)NN * 64 + lane] = 0u;
        return;
    }
    int b_loc = lane >> 5;
    int g = (lane & 31) * 2;
    const unsigned* hp = hws0 + slice + lane;
    int rs = row_start[n];
    int deg8 = row_start[n + 1] - rs;
    float a0, a1;
    {
        unsigned v = hp[(size_t)n * 64];
        a0 = bflo(v); a1 = bfhi(v);
    }
    int myidx = (lane < deg8) ? csr_src[rs + lane] : NN;
    int nch = deg8 >> 3;
    unsigned va[8], vb[8];
    if (nch > 0) {
#pragma unroll
        for (int i = 0; i < 8; ++i) va[i] = hp[(size_t)__shfl(myidx, i) * 64];
    }
    for (int c = 0; c < nch; ++c) {
        if (c + 1 < nch) {
            int base = (c + 1) * 8;
#pragma unroll
            for (int i = 0; i < 8; ++i) {
                int e = base + i;
                int s = (e < 64) ? __shfl(myidx, e) : csr_src[rs + e];
                vb[i] = hp[(size_t)s * 64];
            }
        }
#pragma unroll
        for (int i = 0; i < 8; ++i) { a0 += bflo(va[i]); a1 += bfhi(va[i]); }
        if (c + 1 < nch) {
#pragma unroll
            for (int i = 0; i < 8; ++i) va[i] = vb[i];
        }
    }
    float d = dis[n];
    h0[b_loc][g] = a0 * d + bias0[g];
    h0[b_loc][g + 1] = a1 * d + bias0[g + 1];
    __syncthreads();
    float o0 = 0.f, o1 = 0.f;
#pragma unroll 8
    for (int f = 0; f < 64; ++f) {
        float hv = h0[b_loc][f];
        float2 w = *(const float2*)(W1 + f * 64 + g);
        o0 += hv * w.x;
        o1 += hv * w.y;
    }
    hws1[slice + (size_t)n * 64 + lane] = bfpack2(o0 * d, o1 * d);
}

// ---------------- agg1: split-sliced gather -> h1 (f32 [split][n][2][64]) ----------------

__global__ void k_agg1(const unsigned* __restrict__ hws1, const int* __restrict__ row_start,
                       const int* __restrict__ csr_src, const float* __restrict__ dis,
                       const float* __restrict__ bias1, float* __restrict__ h1) {
    int bid = blockIdx.x;
    int n = bid >> 3;
    int split = bid & 7;
    int lane = threadIdx.x;
    size_t slice = (size_t)split * ((NN + 1) * 64);
    int g = (lane & 31) * 2;
    const unsigned* hp = hws1 + slice + lane;
    int rs = row_start[n];
    int deg8 = row_start[n + 1] - rs;
    float a0, a1;
    {
        unsigned v = hp[(size_t)n * 64];
        a0 = bflo(v); a1 = bfhi(v);
    }
    int myidx = (lane < deg8) ? csr_src[rs + lane] : NN;
    int nch = deg8 >> 3;
    unsigned va[8], vb[8];
    if (nch > 0) {
#pragma unroll
        for (int i = 0; i < 8; ++i) va[i] = hp[(size_t)__shfl(myidx, i) * 64];
    }
    for (int c = 0; c < nch; ++c) {
        if (c + 1 < nch) {
            int base = (c + 1) * 8;
#pragma unroll
            for (int i = 0; i < 8; ++i) {
                int e = base + i;
                int s = (e < 64) ? __shfl(myidx, e) : csr_src[rs + e];
                vb[i] = hp[(size_t)s * 64];
            }
        }
#pragma unroll
        for (int i = 0; i < 8; ++i) { a0 += bflo(va[i]); a1 += bfhi(va[i]); }
        if (c + 1 < nch) {
#pragma unroll
            for (int i = 0; i < 8; ++i) va[i] = vb[i];
        }
    }
    float d = dis[n];
    *(float2*)(h1 + ((size_t)split * NN + n) * 128 + lane * 2) =
        make_float2(a0 * d + bias1[g], a1 * d + bias1[g + 1]);
}

// ---------------- GRUCell: 128 blocks = 16 b x 8 jblk ----------------

__global__ void k_gru(const float* __restrict__ x, const float* __restrict__ hidden,
                      const float* __restrict__ w_ih, const float* __restrict__ b_ih,
                      const float* __restrict__ w_hh, const float* __restrict__ b_hh,
                      float* __restrict__ nh_out, float* __restrict__ nh_ws) {
    __shared__ float s_x[128];
    __shared__ float s_h[512];
    __shared__ float s_p[4 * 64 * 7];
    int tid = threadIdx.x;
    int b = blockIdx.x >> 3;
    int jblk = blockIdx.x & 7;
    if (tid < 128) s_x[tid] = x[b * IN_F + tid];
    for (int i = tid; i < 512; i += 256) s_h[i] = hidden[b * HH + i];
    __syncthreads();
    int jloc = tid & 63;
    int ks = tid >> 6;  // 0..3
    int j = jblk * 64 + jloc;
    float air = 0.f, aiz = 0.f, ain = 0.f, ahr = 0.f, ahz = 0.f, ahn = 0.f;
    {
        const float4* wi0 = (const float4*)(w_ih + (size_t)j * IN_F + ks * 32);
        const float4* wi1 = (const float4*)(w_ih + (size_t)(HH + j) * IN_F + ks * 32);
        const float4* wi2 = (const float4*)(w_ih + (size_t)(2 * HH + j) * IN_F + ks * 32);
        const float4* xs = (const float4*)(s_x + ks * 32);
#pragma unroll
        for (int i = 0; i < 8; ++i) {
            float4 xv = xs[i];
            float4 a = wi0[i], c = wi1[i], d = wi2[i];
            air += xv.x * a.x + xv.y * a.y + xv.z * a.z + xv.w * a.w;
            aiz += xv.x * c.x + xv.y * c.y + xv.z * c.z + xv.w * c.w;
            ain += xv.x * d.x + xv.y * d.y + xv.z * d.z + xv.w * d.w;
        }
    }
    {
        const float4* wh0 = (const float4*)(w_hh + (size_t)j * HH + ks * 128);
        const float4* wh1 = (const float4*)(w_hh + (size_t)(HH + j) * HH + ks * 128);
        const float4* wh2 = (const float4*)(w_hh + (size_t)(2 * HH + j) * HH + ks * 128);
        const float4* hs = (const float4*)(s_h + ks * 128);
#pragma unroll 8
        for (int i = 0; i < 32; ++i) {
            float4 hv = hs[i];
            float4 a = wh0[i], c = wh1[i], d = wh2[i];
            ahr += hv.x * a.x + hv.y * a.y + hv.z * a.z + hv.w * a.w;
            ahz += hv.x * c.x + hv.y * c.y + hv.z * c.z + hv.w * c.w;
            ahn += hv.x * d.x + hv.y * d.y + hv.z * d.z + hv.w * d.w;
        }
    }
    float* pp = s_p + (ks * 64 + jloc) * 7;
    pp[0] = air; pp[1] = aiz; pp[2] = ain; pp[3] = ahr; pp[4] = ahz; pp[5] = ahn;
    __syncthreads();
    if (tid < 64) {
        int jj = jblk * 64 + tid;
        float v0 = 0.f, v1 = 0.f, v2 = 0.f, v3 = 0.f, v4 = 0.f, v5 = 0.f;
#pragma unroll
        for (int s = 0; s < 4; ++s) {
            const float* q = s_p + (s * 64 + tid) * 7;
            v0 += q[0]; v1 += q[1]; v2 += q[2]; v3 += q[3]; v4 += q[4]; v5 += q[5];
        }
        float ir = v0 + b_ih[jj], iz = v1 + b_ih[HH + jj], inn = v2 + b_ih[2 * HH + jj];
        float hr = v3 + b_hh[jj], hz = v4 + b_hh[HH + jj], hn = v5 + b_hh[2 * HH + jj];
        float r = 1.f / (1.f + expf(-(ir + hr)));
        float z = 1.f / (1.f + expf(-(iz + hz)));
        float nn = tanhf(inn + r * hn);
        float hprev = s_h[jj];
        float nh = (1.f - z) * nn + z * hprev;
        nh_out[b * HH + jj] = nh;
        nh_ws[b * HH + jj] = nh;
    }
}

// ---------------- MLP layer 1 ----------------

__global__ void k_mlp1(const float* __restrict__ nh, const float* __restrict__ w1,
                       const float* __restrict__ b1, const float* __restrict__ alpha1,
                       const float* __restrict__ g1, const float* __restrict__ bt1,
                       const float* __restrict__ mu1, const float* __restrict__ var1,
                       float* __restrict__ m1) {
    __shared__ float s_nh[512];
    __shared__ float s_p[4 * 64];
    int tid = threadIdx.x;
    int b = blockIdx.x >> 3;
    int jblk = blockIdx.x & 7;
    for (int i = tid; i < 512; i += 256) s_nh[i] = nh[b * HH + i];
    __syncthreads();
    int jloc = tid & 63;
    int ks = tid >> 6;
    int j = jblk * 64 + jloc;
    const float* wp = w1 + (size_t)(ks * 128) * D1 + j;
    float acc = 0.f;
#pragma unroll 4
    for (int k0 = 0; k0 < 128; k0 += 4) {
        float w0 = wp[0], w1v = wp[D1], w2v = wp[2 * D1], w3v = wp[3 * D1];
        float4 mv = *(const float4*)&s_nh[ks * 128 + k0];
        acc += mv.x * w0 + mv.y * w1v + mv.z * w2v + mv.w * w3v;
        wp += 4 * D1;
    }
    s_p[ks * 64 + jloc] = acc;
    __syncthreads();
    if (tid < 64) {
        int jj = jblk * 64 + tid;
        float v = s_p[tid] + s_p[64 + tid] + s_p[128 + tid] + s_p[192 + tid];
        v += b1[jj];
        float al = alpha1[jj];
        v = v > 0.f ? v : al * v;
        float iv = rsqrtf(var1[jj] + EPSV);
        m1[b * D1 + jj] = g1[jj] * (v - mu1[jj]) * iv + bt1[jj];
    }
}

// ---------------- MLP layer 2: 512 blocks = 64 jt (512 cols) x 8 ok (64 k) ----------------

__global__ void k_mlp2(const float* __restrict__ m1, const float* __restrict__ w2,
                       float* __restrict__ part) {
    __shared__ float s_m1[16 * 64];
    int tid = threadIdx.x;
    int jt = blockIdx.x >> 3;
    int ok = blockIdx.x & 7;
    {
        int b = tid >> 4, kg = tid & 15;
        *(float4*)&s_m1[b * 64 + kg * 4] = *(const float4*)(m1 + b * 512 + ok * 64 + kg * 4);
    }
    __syncthreads();
    int j = jt * 512 + tid * 2;
    const float* wp = w2 + (size_t)(ok * 64) * D2 + j;
    float2 wb0 = *(const float2*)(wp + 0 * (size_t)D2);
    float2 wb1 = *(const float2*)(wp + 1 * (size_t)D2);
    float2 wb2 = *(const float2*)(wp + 2 * (size_t)D2);
    float2 wb3 = *(const float2*)(wp + 3 * (size_t)D2);
    float acc0[16], acc1[16];
#pragma unroll
    for (int b = 0; b < 16; ++b) { acc0[b] = 0.f; acc1[b] = 0.f; }
    for (int k4 = 0; k4 < 64; k4 += 4) {
        float2 c0 = wb0, c1 = wb1, c2 = wb2, c3 = wb3;
        int kp = (k4 + 4 < 64) ? k4 + 4 : 0;
        wb0 = *(const float2*)(wp + (size_t)(kp + 0) * D2);
        wb1 = *(const float2*)(wp + (size_t)(kp + 1) * D2);
        wb2 = *(const float2*)(wp + (size_t)(kp + 2) * D2);
        wb3 = *(const float2*)(wp + (size_t)(kp + 3) * D2);
#pragma unroll
        for (int b = 0; b < 16; ++b) {
            float2 p01 = *(const float2*)&s_m1[b * 64 + k4];
            float2 p23 = *(const float2*)&s_m1[b * 64 + k4 + 2];
            acc0[b] += p01.x * c0.x + p01.y * c1.x + p23.x * c2.x + p23.y * c3.x;
            acc1[b] += p01.x * c0.y + p01.y * c1.y + p23.x * c2.y + p23.y * c3.y;
        }
    }
    float* pb = part + (size_t)(ok * 16) * D2 + j;
#pragma unroll
    for (int b = 0; b < 16; ++b) {
        *(float2*)(pb + (size_t)b * D2) = make_float2(acc0[b], acc1[b]);
    }
}

// ---------------- Output head: fused 8-way mlp2-reduce + bias/PReLU/BN + [gru|h1] @ w_out ----------------

__global__ void k_out(const float* __restrict__ part, const float* __restrict__ h1,
                      const float* __restrict__ b2, const float* __restrict__ alpha2,
                      const float* __restrict__ g2, const float* __restrict__ bt2,
                      const float* __restrict__ mu2, const float* __restrict__ var2,
                      const float* __restrict__ w_out, const float* __restrict__ b_out,
                      float* __restrict__ y) {
    __shared__ float sw[216];
    __shared__ float sb[3];
    int tid = threadIdx.x;
    if (tid < 216) sw[tid] = w_out[tid];
    if (tid < 3) sb[tid] = b_out[tid];
    __syncthreads();
    int t = blockIdx.x * 256 + tid;
    int n = t & (NN - 1);
    int b = t >> 12;
    int j0 = n * 8;
    float4 sA = make_float4(0.f, 0.f, 0.f, 0.f);
    float4 sB = make_float4(0.f, 0.f, 0.f, 0.f);
#pragma unroll
    for (int ok = 0; ok < 8; ++ok) {
        const float* pp = part + (size_t)(ok * 16 + b) * D2 + j0;
        float4 pa = *(const float4*)pp;
        float4 pb = *(const float4*)(pp + 4);
        sA.x += pa.x; sA.y += pa.y; sA.z += pa.z; sA.w += pa.w;
        sB.x += pb.x; sB.y += pb.y; sB.z += pb.z; sB.w += pb.w;
    }
    float raw[8] = {sA.x, sA.y, sA.z, sA.w, sB.x, sB.y, sB.z, sB.w};
    float4 bja = *(const float4*)(b2 + j0),    bjb = *(const float4*)(b2 + j0 + 4);
    float4 ala = *(const float4*)(alpha2 + j0), alb = *(const float4*)(alpha2 + j0 + 4);
    float4 gaa = *(const float4*)(g2 + j0),    gab = *(const float4*)(g2 + j0 + 4);
    float4 bea = *(const float4*)(bt2 + j0),   beb = *(const float4*)(bt2 + j0 + 4);
    float4 mua = *(const float4*)(mu2 + j0),   mub = *(const float4*)(mu2 + j0 + 4);
    float4 vaa = *(const float4*)(var2 + j0),  vab = *(const float4*)(var2 + j0 + 4);
    float bj[8] = {bja.x, bja.y, bja.z, bja.w, bjb.x, bjb.y, bjb.z, bjb.w};
    float al[8] = {ala.x, ala.y, ala.z, ala.w, alb.x, alb.y, alb.z, alb.w};
    float ga[8] = {gaa.x, gaa.y, gaa.z, gaa.w, gab.x, gab.y, gab.z, gab.w};
    float be[8] = {bea.x, bea.y, bea.z, bea.w, beb.x, beb.y, beb.z, beb.w};
    float mu[8] = {mua.x, mua.y, mua.z, mua.w, mub.x, mub.y, mub.z, mub.w};
    float va[8] = {vaa.x, vaa.y, vaa.z, vaa.w, vab.x, vab.y, vab.z, vab.w};
    float y0 = sb[0], y1 = sb[1], y2 = sb[2];
#pragma unroll
    for (int g = 0; g < 8; ++g) {
        float v = raw[g] + bj[g];
        v = v > 0.f ? v : al[g] * v;
        v = ga[g] * (v - mu[g]) * rsqrtf(va[g] + EPSV) + be[g];
        y0 += v * sw[g * 3 + 0];
        y1 += v * sw[g * 3 + 1];
        y2 += v * sw[g * 3 + 2];
    }
    const float* hp = h1 + ((size_t)(b >> 1) * NN + n) * 128 + (b & 1) * 64;
#pragma unroll
    for (int f = 0; f < 64; f += 4) {
        float4 hv = *(const float4*)(hp + f);
        y0 += hv.x * sw[(8 + f) * 3 + 0] + hv.y * sw[(9 + f) * 3 + 0] +
              hv.z * sw[(10 + f) * 3 + 0] + hv.w * sw[(11 + f) * 3 + 0];
        y1 += hv.x * sw[(8 + f) * 3 + 1] + hv.y * sw[(9 + f) * 3 + 1] +
              hv.z * sw[(10 + f) * 3 + 1] + hv.w * sw[(11 + f) * 3 + 1];
        y2 += hv.x * sw[(8 + f) * 3 + 2] + hv.y * sw[(9 + f) * 3 + 2] +
              hv.z * sw[(10 + f) * 3 + 2] + hv.w * sw[(11 + f) * 3 + 2];
    }
    float* yo = y + (size_t)b * (NN * 3) + n * 3;
    yo[0] = y0;
    yo[1] = y1;
    yo[2] = y2;
}

// ---------------- launcher ----------------

extern "C" void kernel_launch(void* const* d_in, const int* in_sizes, int n_in,
                              void* d_out, int out_size, void* d_ws, size_t ws_size,
                              hipStream_t stream) {
    const float* x      = (const float*)d_in[0];
    const float* pos    = (const float*)d_in[1];
    const float* hidden = (const float*)d_in[2];
    const int*   ei     = (const int*)d_in[3];
    const float* W0     = (const float*)d_in[4];
    const float* b0     = (const float*)d_in[5];
    const float* W1     = (const float*)d_in[6];
    const float* b1     = (const float*)d_in[7];
    const float* w_ih   = (const float*)d_in[8];
    const float* b_ih   = (const float*)d_in[9];
    const float* w_hh   = (const float*)d_in[10];
    const float* b_hh   = (const float*)d_in[11];
    const float* mlp_w1 = (const float*)d_in[12];
    const float* mlp_b1 = (const float*)d_in[13];
    const float* alpha1 = (const float*)d_in[14];
    const float* bn1g   = (const float*)d_in[15];
    const float* bn1b   = (const float*)d_in[16];
    const float* bn1m   = (const float*)d_in[17];
    const float* bn1v   = (const float*)d_in[18];
    const float* mlp_w2 = (const float*)d_in[19];
    const float* mlp_b2 = (const float*)d_in[20];
    const float* alpha2 = (const float*)d_in[21];
    const float* bn2g   = (const float*)d_in[22];
    const float* bn2b   = (const float*)d_in[23];
    const float* bn2m   = (const float*)d_in[24];
    const float* bn2v   = (const float*)d_in[25];
    const float* w_out  = (const float*)d_in[26];
    const float* b_out  = (const float*)d_in[27];

    float* out = (float*)d_out;
    float* ws = (float*)d_ws;

    // workspace layout (float offsets)
    float* bufA = ws;                  // 4M floats: hws0 (bf16 sliced 8.4MB) then h1 (f32 16MB)
    float* bufB = ws + 4194304;        // 4M floats: hws1 (bf16 sliced 8.4MB), then part (f32 16MB)
    float* nh   = ws + 8388608;        // 16*512
    float* m1s  = ws + 8396800;        // 16*512
    float* dis  = ws + 8404992;        // 4096
    int* wsi       = (int*)(ws + 8409088);
    int* cnt       = wsi;                       // 4096
    int* row_start = wsi + 4096;                // 4097
    int* cursor    = wsi + 4096 + 4097;         // 4096
    int* csr       = wsi + 4096 + 4097 + 4096;  // PADMAX (94208)

    unsigned* hws0 = (unsigned*)bufA;
    unsigned* hws1 = (unsigned*)bufB;
    float* h1   = bufA;   // f32 [split][NN][128], written by k_agg1 after hws0 consumed
    float* part = bufB;   // f32 partials (8*16 x D2), written after hws1 consumed

    const int* srcp = ei;
    const int* dstp = ei + EE;

    hipMemsetAsync(cnt, 0, 4096 * sizeof(int), stream);
    k_hist<<<EE / 256, 256, 0, stream>>>(dstp, cnt);
    k_scan<<<1, 1024, 0, stream>>>(cnt, row_start, cursor, dis);
    k_padfill<<<PADMAX / 256, 256, 0, stream>>>(csr);
    k_fill<<<EE / 256, 256, 0, stream>>>(srcp, dstp, cursor, csr);
    k_hw0<<<NN + 1, 256, 0, stream>>>(pos, W0, dis, hws0);
    k_layer0<<<(NN + 1) * 8, 64, 0, stream>>>(hws0, row_start, csr, dis, b0, W1, hws1);
    k_agg1<<<NN * 8, 64, 0, stream>>>(hws1, row_start, csr, dis, b1, h1);
    k_gru<<<128, 256, 0, stream>>>(x, hidden, w_ih, b_ih, w_hh, b_hh, out + BB * NN * 3, nh);
    k_mlp1<<<128, 256, 0, stream>>>(nh, mlp_w1, mlp_b1, alpha1, bn1g, bn1b, bn1m, bn1v, m1s);
    k_mlp2<<<512, 256, 0, stream>>>(m1s, mlp_w2, part);
    k_out<<<(BB * NN) / 256, 256, 0, stream>>>(part, h1, mlp_b2, alpha2, bn2g, bn2b, bn2m,
                                               bn2v, w_out, b_out, out);
}

// Round 7
// 152.332 us; speedup vs baseline: 1.1234x; 1.1234x over previous
//
#include <hip/hip_runtime.h>
#include <math.h>

#define BB 16
#define NN 4096
#define EE 65536
#define IN_F 128
#define HH 512
#define F1 64
#define D1 512
#define D2 32768
#define EPSV 1e-5f
#define PADMAX 94208  // EE + NN*7 worst-case padded CSR

// bf16 helpers (RNE pack, cheap unpack)
__device__ __forceinline__ unsigned bfpack2(float a, float b) {
    unsigned ua = __float_as_uint(a), ub = __float_as_uint(b);
    ua += 0x7fffu + ((ua >> 16) & 1u);
    ub += 0x7fffu + ((ub >> 16) & 1u);
    return (ua >> 16) | (ub & 0xffff0000u);
}
__device__ __forceinline__ float bflo(unsigned u) { return __uint_as_float(u << 16); }
__device__ __forceinline__ float bfhi(unsigned u) { return __uint_as_float(u & 0xffff0000u); }

// ---------------- GCN support: histogram / scan / pad / CSR fill ----------------

__global__ void k_hist(const int* __restrict__ dst, int* __restrict__ cnt) {
    int i = blockIdx.x * 256 + threadIdx.x;
    if (i < EE) atomicAdd(&cnt[dst[i]], 1);
}

// prefix-sum of PADDED counts (each node's row padded to multiple of 8)
__global__ void k_scan(const int* __restrict__ cnt, int* __restrict__ row_start,
                       int* __restrict__ cursor, float* __restrict__ dis) {
    __shared__ int lds[1024];
    int tid = threadIdx.x;
    int v0 = cnt[tid * 4 + 0];
    int v1 = cnt[tid * 4 + 1];
    int v2 = cnt[tid * 4 + 2];
    int v3 = cnt[tid * 4 + 3];
    int p0 = (v0 + 7) & ~7, p1 = (v1 + 7) & ~7, p2 = (v2 + 7) & ~7, p3 = (v3 + 7) & ~7;
    int s = p0 + p1 + p2 + p3;
    lds[tid] = s;
    __syncthreads();
    for (int off = 1; off < 1024; off <<= 1) {
        int t = (tid >= off) ? lds[tid - off] : 0;
        __syncthreads();
        lds[tid] += t;
        __syncthreads();
    }
    int e = (tid > 0) ? lds[tid - 1] : 0;
    int idx = tid * 4;
    row_start[idx + 0] = e; cursor[idx + 0] = e; dis[idx + 0] = rsqrtf((float)(v0 + 1)); e += p0;
    row_start[idx + 1] = e; cursor[idx + 1] = e; dis[idx + 1] = rsqrtf((float)(v1 + 1)); e += p1;
    row_start[idx + 2] = e; cursor[idx + 2] = e; dis[idx + 2] = rsqrtf((float)(v2 + 1)); e += p2;
    row_start[idx + 3] = e; cursor[idx + 3] = e; dis[idx + 3] = rsqrtf((float)(v3 + 1)); e += p3;
    if (tid == 1023) row_start[4096] = lds[1023];
}

__global__ void k_padfill(int* __restrict__ csr) {
    int i = blockIdx.x * 256 + threadIdx.x;
    csr[i] = NN;  // sentinel -> zero block
}

__global__ void k_fill(const int* __restrict__ src, const int* __restrict__ dst,
                       int* __restrict__ cursor, int* __restrict__ csr_src) {
    int i = blockIdx.x * 256 + threadIdx.x;
    if (i < EE) {
        int d = dst[i];
        int p = atomicAdd(&cursor[d], 1);
        csr_src[p] = src[i];
    }
}

// ---------------- hws0 = bf16( dis[n] * (pos @ W0) ), layout [n][b][g] bf16 ----------------
// grid NN+1: block NN writes the sentinel zero block

__global__ void k_hw0(const float* __restrict__ pos, const float* __restrict__ W0,
                      const float* __restrict__ dis, unsigned* __restrict__ hws0) {
    int n = blockIdx.x;
    int tid = threadIdx.x;
    if (n == NN) {
        *(uint2*)(hws0 + (size_t)NN * 512 + tid * 2) = make_uint2(0u, 0u);
        return;
    }
    int b = tid >> 4;
    int g0 = (tid & 15) * 4;
    float d = dis[n];
    const float* p = pos + b * (NN * 3) + n * 3;
    float p0 = p[0], p1 = p[1], p2 = p[2];
    float4 w0 = *(const float4*)(W0 + g0);
    float4 w1 = *(const float4*)(W0 + 64 + g0);
    float4 w2 = *(const float4*)(W0 + 128 + g0);
    float o0 = d * (p0 * w0.x + p1 * w1.x + p2 * w2.x);
    float o1 = d * (p0 * w0.y + p1 * w1.y + p2 * w2.y);
    float o2 = d * (p0 * w0.z + p1 * w1.z + p2 * w2.z);
    float o3 = d * (p0 * w0.w + p1 * w1.w + p2 * w2.w);
    uint2 pk;
    pk.x = bfpack2(o0, o1);
    pk.y = bfpack2(o2, o3);
    *(uint2*)(hws0 + (size_t)n * 512 + tid * 2) = pk;
}

// ---------------- layer0: LDS-idx + 3-stage pipelined gather + W1 matmul -> hws1 ----------------
// Indices staged in LDS (ds_read, lgkm counter) so gather issue never waits on
// vmcnt; chunks c+1,c+2 in flight while consuming c -> 16-24 outstanding loads.

__global__ void k_layer0(const unsigned* __restrict__ hws0, const int* __restrict__ row_start,
                         const int* __restrict__ csr_src, const float* __restrict__ dis,
                         const float* __restrict__ bias0, const float* __restrict__ W1,
                         unsigned* __restrict__ hws1) {
    __shared__ float h0[16][72];
    __shared__ int sidx[512];
    int n = blockIdx.x;
    int tid = threadIdx.x;
    if (n == NN) {
        *(uint2*)(hws1 + (size_t)NN * 512 + tid * 2) = make_uint2(0u, 0u);
        return;
    }
    int b = tid >> 4;
    int g0 = (tid & 15) * 4;
    int rs = row_start[n];
    int deg8 = row_start[n + 1] - rs;
    for (int i = tid; i < deg8; i += 256) sidx[i] = csr_src[rs + i];
    __syncthreads();
    const uint2* hp = (const uint2*)hws0 + tid;
    float a0, a1, a2, a3;
    {
        uint2 v = hp[(size_t)n * 256];
        a0 = bflo(v.x); a1 = bfhi(v.x); a2 = bflo(v.y); a3 = bfhi(v.y);
    }
    int nch = deg8 >> 3;
    uint2 A[8], B[8], C[8];
#pragma unroll
    for (int i = 0; i < 8; ++i) { A[i] = make_uint2(0u, 0u); B[i] = A[i]; C[i] = A[i]; }
    if (nch > 0) {
#pragma unroll
        for (int i = 0; i < 8; ++i) A[i] = hp[(size_t)sidx[i] * 256];
    }
    if (nch > 1) {
#pragma unroll
        for (int i = 0; i < 8; ++i) B[i] = hp[(size_t)sidx[8 + i] * 256];
    }
    for (int c = 0; c < nch; ++c) {
        if (c + 2 < nch) {
            int base = (c + 2) * 8;
#pragma unroll
            for (int i = 0; i < 8; ++i) C[i] = hp[(size_t)sidx[base + i] * 256];
        }
#pragma unroll
        for (int i = 0; i < 8; ++i) {
            a0 += bflo(A[i].x); a1 += bfhi(A[i].x);
            a2 += bflo(A[i].y); a3 += bfhi(A[i].y);
        }
#pragma unroll
        for (int i = 0; i < 8; ++i) { A[i] = B[i]; B[i] = C[i]; }
    }
    float d = dis[n];
    float4 bg = *(const float4*)(bias0 + g0);
    *(float4*)&h0[b][g0] = make_float4(a0 * d + bg.x, a1 * d + bg.y, a2 * d + bg.z, a3 * d + bg.w);
    __syncthreads();
    float o0 = 0.f, o1 = 0.f, o2 = 0.f, o3 = 0.f;
#pragma unroll 8
    for (int f = 0; f < 64; ++f) {
        float hv = h0[b][f];
        float4 w = *(const float4*)(W1 + f * 64 + g0);
        o0 += hv * w.x; o1 += hv * w.y; o2 += hv * w.z; o3 += hv * w.w;
    }
    uint2 pk;
    pk.x = bfpack2(o0 * d, o1 * d);
    pk.y = bfpack2(o2 * d, o3 * d);
    *(uint2*)(hws1 + (size_t)n * 512 + tid * 2) = pk;
}

// ---------------- agg1: LDS-idx + 3-stage pipelined gather -> h1 (f32 [n][b][g]) ----------------

__global__ void k_agg1(const unsigned* __restrict__ hws1, const int* __restrict__ row_start,
                       const int* __restrict__ csr_src, const float* __restrict__ dis,
                       const float* __restrict__ bias1, float* __restrict__ h1) {
    __shared__ int sidx[512];
    int n = blockIdx.x;
    int tid = threadIdx.x;
    int g0 = (tid & 15) * 4;
    int rs = row_start[n];
    int deg8 = row_start[n + 1] - rs;
    for (int i = tid; i < deg8; i += 256) sidx[i] = csr_src[rs + i];
    __syncthreads();
    const uint2* hp = (const uint2*)hws1 + tid;
    float a0, a1, a2, a3;
    {
        uint2 v = hp[(size_t)n * 256];
        a0 = bflo(v.x); a1 = bfhi(v.x); a2 = bflo(v.y); a3 = bfhi(v.y);
    }
    int nch = deg8 >> 3;
    uint2 A[8], B[8], C[8];
#pragma unroll
    for (int i = 0; i < 8; ++i) { A[i] = make_uint2(0u, 0u); B[i] = A[i]; C[i] = A[i]; }
    if (nch > 0) {
#pragma unroll
        for (int i = 0; i < 8; ++i) A[i] = hp[(size_t)sidx[i] * 256];
    }
    if (nch > 1) {
#pragma unroll
        for (int i = 0; i < 8; ++i) B[i] = hp[(size_t)sidx[8 + i] * 256];
    }
    for (int c = 0; c < nch; ++c) {
        if (c + 2 < nch) {
            int base = (c + 2) * 8;
#pragma unroll
            for (int i = 0; i < 8; ++i) C[i] = hp[(size_t)sidx[base + i] * 256];
        }
#pragma unroll
        for (int i = 0; i < 8; ++i) {
            a0 += bflo(A[i].x); a1 += bfhi(A[i].x);
            a2 += bflo(A[i].y); a3 += bfhi(A[i].y);
        }
#pragma unroll
        for (int i = 0; i < 8; ++i) { A[i] = B[i]; B[i] = C[i]; }
    }
    float d = dis[n];
    float4 bg = *(const float4*)(bias1 + g0);
    *(float4*)(h1 + (size_t)n * 1024 + tid * 4) =
        make_float4(a0 * d + bg.x, a1 * d + bg.y, a2 * d + bg.z, a3 * d + bg.w);
}

// ---------------- GRUCell: 128 blocks = 16 b x 8 jblk ----------------

__global__ void k_gru(const float* __restrict__ x, const float* __restrict__ hidden,
                      const float* __restrict__ w_ih, const float* __restrict__ b_ih,
                      const float* __restrict__ w_hh, const float* __restrict__ b_hh,
                      float* __restrict__ nh_out, float* __restrict__ nh_ws) {
    __shared__ float s_x[128];
    __shared__ float s_h[512];
    __shared__ float s_p[4 * 64 * 7];
    int tid = threadIdx.x;
    int b = blockIdx.x >> 3;
    int jblk = blockIdx.x & 7;
    if (tid < 128) s_x[tid] = x[b * IN_F + tid];
    for (int i = tid; i < 512; i += 256) s_h[i] = hidden[b * HH + i];
    __syncthreads();
    int jloc = tid & 63;
    int ks = tid >> 6;  // 0..3
    int j = jblk * 64 + jloc;
    float air = 0.f, aiz = 0.f, ain = 0.f, ahr = 0.f, ahz = 0.f, ahn = 0.f;
    {
        const float4* wi0 = (const float4*)(w_ih + (size_t)j * IN_F + ks * 32);
        const float4* wi1 = (const float4*)(w_ih + (size_t)(HH + j) * IN_F + ks * 32);
        const float4* wi2 = (const float4*)(w_ih + (size_t)(2 * HH + j) * IN_F + ks * 32);
        const float4* xs = (const float4*)(s_x + ks * 32);
#pragma unroll
        for (int i = 0; i < 8; ++i) {
            float4 xv = xs[i];
            float4 a = wi0[i], c = wi1[i], d = wi2[i];
            air += xv.x * a.x + xv.y * a.y + xv.z * a.z + xv.w * a.w;
            aiz += xv.x * c.x + xv.y * c.y + xv.z * c.z + xv.w * c.w;
            ain += xv.x * d.x + xv.y * d.y + xv.z * d.z + xv.w * d.w;
        }
    }
    {
        const float4* wh0 = (const float4*)(w_hh + (size_t)j * HH + ks * 128);
        const float4* wh1 = (const float4*)(w_hh + (size_t)(HH + j) * HH + ks * 128);
        const float4* wh2 = (const float4*)(w_hh + (size_t)(2 * HH + j) * HH + ks * 128);
        const float4* hs = (const float4*)(s_h + ks * 128);
#pragma unroll 8
        for (int i = 0; i < 32; ++i) {
            float4 hv = hs[i];
            float4 a = wh0[i], c = wh1[i], d = wh2[i];
            ahr += hv.x * a.x + hv.y * a.y + hv.z * a.z + hv.w * a.w;
            ahz += hv.x * c.x + hv.y * c.y + hv.z * c.z + hv.w * c.w;
            ahn += hv.x * d.x + hv.y * d.y + hv.z * d.z + hv.w * d.w;
        }
    }
    float* pp = s_p + (ks * 64 + jloc) * 7;
    pp[0] = air; pp[1] = aiz; pp[2] = ain; pp[3] = ahr; pp[4] = ahz; pp[5] = ahn;
    __syncthreads();
    if (tid < 64) {
        int jj = jblk * 64 + tid;
        float v0 = 0.f, v1 = 0.f, v2 = 0.f, v3 = 0.f, v4 = 0.f, v5 = 0.f;
#pragma unroll
        for (int s = 0; s < 4; ++s) {
            const float* q = s_p + (s * 64 + tid) * 7;
            v0 += q[0]; v1 += q[1]; v2 += q[2]; v3 += q[3]; v4 += q[4]; v5 += q[5];
        }
        float ir = v0 + b_ih[jj], iz = v1 + b_ih[HH + jj], inn = v2 + b_ih[2 * HH + jj];
        float hr = v3 + b_hh[jj], hz = v4 + b_hh[HH + jj], hn = v5 + b_hh[2 * HH + jj];
        float r = 1.f / (1.f + expf(-(ir + hr)));
        float z = 1.f / (1.f + expf(-(iz + hz)));
        float nn = tanhf(inn + r * hn);
        float hprev = s_h[jj];
        float nh = (1.f - z) * nn + z * hprev;
        nh_out[b * HH + jj] = nh;
        nh_ws[b * HH + jj] = nh;
    }
}

// ---------------- MLP layer 1 ----------------

__global__ void k_mlp1(const float* __restrict__ nh, const float* __restrict__ w1,
                       const float* __restrict__ b1, const float* __restrict__ alpha1,
                       const float* __restrict__ g1, const float* __restrict__ bt1,
                       const float* __restrict__ mu1, const float* __restrict__ var1,
                       float* __restrict__ m1) {
    __shared__ float s_nh[512];
    __shared__ float s_p[4 * 64];
    int tid = threadIdx.x;
    int b = blockIdx.x >> 3;
    int jblk = blockIdx.x & 7;
    for (int i = tid; i < 512; i += 256) s_nh[i] = nh[b * HH + i];
    __syncthreads();
    int jloc = tid & 63;
    int ks = tid >> 6;
    int j = jblk * 64 + jloc;
    const float* wp = w1 + (size_t)(ks * 128) * D1 + j;
    float acc = 0.f;
#pragma unroll 4
    for (int k0 = 0; k0 < 128; k0 += 4) {
        float w0 = wp[0], w1v = wp[D1], w2v = wp[2 * D1], w3v = wp[3 * D1];
        float4 mv = *(const float4*)&s_nh[ks * 128 + k0];
        acc += mv.x * w0 + mv.y * w1v + mv.z * w2v + mv.w * w3v;
        wp += 4 * D1;
    }
    s_p[ks * 64 + jloc] = acc;
    __syncthreads();
    if (tid < 64) {
        int jj = jblk * 64 + tid;
        float v = s_p[tid] + s_p[64 + tid] + s_p[128 + tid] + s_p[192 + tid];
        v += b1[jj];
        float al = alpha1[jj];
        v = v > 0.f ? v : al * v;
        float iv = rsqrtf(var1[jj] + EPSV);
        m1[b * D1 + jj] = g1[jj] * (v - mu1[jj]) * iv + bt1[jj];
    }
}

// ---------------- MLP layer 2: 512 blocks = 64 jt (512 cols) x 8 ok (64 k) ----------------

__global__ void k_mlp2(const float* __restrict__ m1, const float* __restrict__ w2,
                       float* __restrict__ part) {
    __shared__ float s_m1[16 * 64];
    int tid = threadIdx.x;
    int jt = blockIdx.x >> 3;
    int ok = blockIdx.x & 7;
    {
        int b = tid >> 4, kg = tid & 15;
        *(float4*)&s_m1[b * 64 + kg * 4] = *(const float4*)(m1 + b * 512 + ok * 64 + kg * 4);
    }
    __syncthreads();
    int j = jt * 512 + tid * 2;
    const float* wp = w2 + (size_t)(ok * 64) * D2 + j;
    float2 wb0 = *(const float2*)(wp + 0 * (size_t)D2);
    float2 wb1 = *(const float2*)(wp + 1 * (size_t)D2);
    float2 wb2 = *(const float2*)(wp + 2 * (size_t)D2);
    float2 wb3 = *(const float2*)(wp + 3 * (size_t)D2);
    float acc0[16], acc1[16];
#pragma unroll
    for (int b = 0; b < 16; ++b) { acc0[b] = 0.f; acc1[b] = 0.f; }
    for (int k4 = 0; k4 < 64; k4 += 4) {
        float2 c0 = wb0, c1 = wb1, c2 = wb2, c3 = wb3;
        int kp = (k4 + 4 < 64) ? k4 + 4 : 0;
        wb0 = *(const float2*)(wp + (size_t)(kp + 0) * D2);
        wb1 = *(const float2*)(wp + (size_t)(kp + 1) * D2);
        wb2 = *(const float2*)(wp + (size_t)(kp + 2) * D2);
        wb3 = *(const float2*)(wp + (size_t)(kp + 3) * D2);
#pragma unroll
        for (int b = 0; b < 16; ++b) {
            float2 p01 = *(const float2*)&s_m1[b * 64 + k4];
            float2 p23 = *(const float2*)&s_m1[b * 64 + k4 + 2];
            acc0[b] += p01.x * c0.x + p01.y * c1.x + p23.x * c2.x + p23.y * c3.x;
            acc1[b] += p01.x * c0.y + p01.y * c1.y + p23.x * c2.y + p23.y * c3.y;
        }
    }
    float* pb = part + (size_t)(ok * 16) * D2 + j;
#pragma unroll
    for (int b = 0; b < 16; ++b) {
        *(float2*)(pb + (size_t)b * D2) = make_float2(acc0[b], acc1[b]);
    }
}

// ---------------- Output head: fused 8-way mlp2-reduce + bias/PReLU/BN + [gru|h1] @ w_out ----------------

__global__ void k_out(const float* __restrict__ part, const float* __restrict__ h1,
                      const float* __restrict__ b2, const float* __restrict__ alpha2,
                      const float* __restrict__ g2, const float* __restrict__ bt2,
                      const float* __restrict__ mu2, const float* __restrict__ var2,
                      const float* __restrict__ w_out, const float* __restrict__ b_out,
                      float* __restrict__ y) {
    __shared__ float sw[216];
    __shared__ float sb[3];
    int tid = threadIdx.x;
    if (tid < 216) sw[tid] = w_out[tid];
    if (tid < 3) sb[tid] = b_out[tid];
    __syncthreads();
    int t = blockIdx.x * 256 + tid;
    int n = t & (NN - 1);
    int b = t >> 12;
    int j0 = n * 8;
    float4 sA = make_float4(0.f, 0.f, 0.f, 0.f);
    float4 sB = make_float4(0.f, 0.f, 0.f, 0.f);
#pragma unroll
    for (int ok = 0; ok < 8; ++ok) {
        const float* pp = part + (size_t)(ok * 16 + b) * D2 + j0;
        float4 pa = *(const float4*)pp;
        float4 pb = *(const float4*)(pp + 4);
        sA.x += pa.x; sA.y += pa.y; sA.z += pa.z; sA.w += pa.w;
        sB.x += pb.x; sB.y += pb.y; sB.z += pb.z; sB.w += pb.w;
    }
    float raw[8] = {sA.x, sA.y, sA.z, sA.w, sB.x, sB.y, sB.z, sB.w};
    float4 bja = *(const float4*)(b2 + j0),    bjb = *(const float4*)(b2 + j0 + 4);
    float4 ala = *(const float4*)(alpha2 + j0), alb = *(const float4*)(alpha2 + j0 + 4);
    float4 gaa = *(const float4*)(g2 + j0),    gab = *(const float4*)(g2 + j0 + 4);
    float4 bea = *(const float4*)(bt2 + j0),   beb = *(const float4*)(bt2 + j0 + 4);
    float4 mua = *(const float4*)(mu2 + j0),   mub = *(const float4*)(mu2 + j0 + 4);
    float4 vaa = *(const float4*)(var2 + j0),  vab = *(const float4*)(var2 + j0 + 4);
    float bj[8] = {bja.x, bja.y, bja.z, bja.w, bjb.x, bjb.y, bjb.z, bjb.w};
    float al[8] = {ala.x, ala.y, ala.z, ala.w, alb.x, alb.y, alb.z, alb.w};
    float ga[8] = {gaa.x, gaa.y, gaa.z, gaa.w, gab.x, gab.y, gab.z, gab.w};
    float be[8] = {bea.x, bea.y, bea.z, bea.w, beb.x, beb.y, beb.z, beb.w};
    float mu[8] = {mua.x, mua.y, mua.z, mua.w, mub.x, mub.y, mub.z, mub.w};
    float va[8] = {vaa.x, vaa.y, vaa.z, vaa.w, vab.x, vab.y, vab.z, vab.w};
    float y0 = sb[0], y1 = sb[1], y2 = sb[2];
#pragma unroll
    for (int g = 0; g < 8; ++g) {
        float v = raw[g] + bj[g];
        v = v > 0.f ? v : al[g] * v;
        v = ga[g] * (v - mu[g]) * rsqrtf(va[g] + EPSV) + be[g];
        y0 += v * sw[g * 3 + 0];
        y1 += v * sw[g * 3 + 1];
        y2 += v * sw[g * 3 + 2];
    }
    const float* hp = h1 + (size_t)n * 1024 + b * 64;
#pragma unroll
    for (int f = 0; f < 64; f += 4) {
        float4 hv = *(const float4*)(hp + f);
        y0 += hv.x * sw[(8 + f) * 3 + 0] + hv.y * sw[(9 + f) * 3 + 0] +
              hv.z * sw[(10 + f) * 3 + 0] + hv.w * sw[(11 + f) * 3 + 0];
        y1 += hv.x * sw[(8 + f) * 3 + 1] + hv.y * sw[(9 + f) * 3 + 1] +
              hv.z * sw[(10 + f) * 3 + 1] + hv.w * sw[(11 + f) * 3 + 1];
        y2 += hv.x * sw[(8 + f) * 3 + 2] + hv.y * sw[(9 + f) * 3 + 2] +
              hv.z * sw[(10 + f) * 3 + 2] + hv.w * sw[(11 + f) * 3 + 2];
    }
    float* yo = y + (size_t)b * (NN * 3) + n * 3;
    yo[0] = y0;
    yo[1] = y1;
    yo[2] = y2;
}

// ---------------- launcher ----------------

extern "C" void kernel_launch(void* const* d_in, const int* in_sizes, int n_in,
                              void* d_out, int out_size, void* d_ws, size_t ws_size,
                              hipStream_t stream) {
    const float* x      = (const float*)d_in[0];
    const float* pos    = (const float*)d_in[1];
    const float* hidden = (const float*)d_in[2];
    const int*   ei     = (const int*)d_in[3];
    const float* W0     = (const float*)d_in[4];
    const float* b0     = (const float*)d_in[5];
    const float* W1     = (const float*)d_in[6];
    const float* b1     = (const float*)d_in[7];
    const float* w_ih   = (const float*)d_in[8];
    const float* b_ih   = (const float*)d_in[9];
    const float* w_hh   = (const float*)d_in[10];
    const float* b_hh   = (const float*)d_in[11];
    const float* mlp_w1 = (const float*)d_in[12];
    const float* mlp_b1 = (const float*)d_in[13];
    const float* alpha1 = (const float*)d_in[14];
    const float* bn1g   = (const float*)d_in[15];
    const float* bn1b   = (const float*)d_in[16];
    const float* bn1m   = (const float*)d_in[17];
    const float* bn1v   = (const float*)d_in[18];
    const float* mlp_w2 = (const float*)d_in[19];
    const float* mlp_b2 = (const float*)d_in[20];
    const float* alpha2 = (const float*)d_in[21];
    const float* bn2g   = (const float*)d_in[22];
    const float* bn2b   = (const float*)d_in[23];
    const float* bn2m   = (const float*)d_in[24];
    const float* bn2v   = (const float*)d_in[25];
    const float* w_out  = (const float*)d_in[26];
    const float* b_out  = (const float*)d_in[27];

    float* out = (float*)d_out;
    float* ws = (float*)d_ws;

    // workspace layout (float offsets)
    float* bufA = ws;                  // 4M floats: hws0 (bf16 ~8.4MB incl sentinel) then h1 (f32 16MB)
    float* bufB = ws + 4194304;        // 4M floats: hws1 (bf16 ~8.4MB), then part (f32 16MB)
    float* nh   = ws + 8388608;        // 16*512
    float* m1s  = ws + 8396800;        // 16*512
    float* dis  = ws + 8404992;        // 4096
    int* wsi       = (int*)(ws + 8409088);
    int* cnt       = wsi;                       // 4096
    int* row_start = wsi + 4096;                // 4097
    int* cursor    = wsi + 4096 + 4097;         // 4096
    int* csr       = wsi + 4096 + 4097 + 4096;  // PADMAX (94208)

    unsigned* hws0 = (unsigned*)bufA;
    unsigned* hws1 = (unsigned*)bufB;
    float* h1   = bufA;   // f32, written by k_agg1 after hws0 consumed
    float* part = bufB;   // f32 partials (8*16 x D2), written after hws1 consumed

    const int* srcp = ei;
    const int* dstp = ei + EE;

    hipMemsetAsync(cnt, 0, 4096 * sizeof(int), stream);
    k_hist<<<EE / 256, 256, 0, stream>>>(dstp, cnt);
    k_scan<<<1, 1024, 0, stream>>>(cnt, row_start, cursor, dis);
    k_padfill<<<PADMAX / 256, 256, 0, stream>>>(csr);
    k_fill<<<EE / 256, 256, 0, stream>>>(srcp, dstp, cursor, csr);
    k_hw0<<<NN + 1, 256, 0, stream>>>(pos, W0, dis, hws0);
    k_layer0<<<NN + 1, 256, 0, stream>>>(hws0, row_start, csr, dis, b0, W1, hws1);
    k_agg1<<<NN, 256, 0, stream>>>(hws1, row_start, csr, dis, b1, h1);
    k_gru<<<128, 256, 0, stream>>>(x, hidden, w_ih, b_ih, w_hh, b_hh, out + BB * NN * 3, nh);
    k_mlp1<<<128, 256, 0, stream>>>(nh, mlp_w1, mlp_b1, alpha1, bn1g, bn1b, bn1m, bn1v, m1s);
    k_mlp2<<<512, 256, 0, stream>>>(m1s, mlp_w2, part);
    k_out<<<(BB * NN) / 256, 256, 0, stream>>>(part, h1, mlp_b2, alpha2, bn2g, bn2b, bn2m,
                                               bn2v, w_out, b_out, out);
}

// Round 8
// 94.921 us; speedup vs baseline: 1.8029x; 1.6048x over previous
//
#include <hip/hip_runtime.h>
#include <math.h>

#define BB 16
#define NN 4096
#define EE 65536
#define IN_F 128
#define HH 512
#define D1 512
#define D2 32768
#define EPSV 1e-5f
#define PADMAX 94208  // EE + NN*7 worst-case padded CSR

// ---------------- GCN support: histogram / scan(+small-matrix precompute) / pad / fill ----------------

__global__ void k_hist(const int* __restrict__ dst, int* __restrict__ cnt) {
    int i = blockIdx.x * 256 + threadIdx.x;
    if (i < EE) atomicAdd(&cnt[dst[i]], 1);
}

// prefix-sum of PADDED counts (rows padded to multiple of 8) + dis + collapsed small matrices
// sm layout: [0..8] W0M3 (3x3 row-major k*3+c), [9..11] b0@M3, [12..14] b1@Wh
__global__ void k_scan(const int* __restrict__ cnt, int* __restrict__ row_start,
                       int* __restrict__ cursor, float* __restrict__ dis,
                       const float* __restrict__ W0, const float* __restrict__ b0,
                       const float* __restrict__ W1, const float* __restrict__ b1,
                       const float* __restrict__ w_out, float* __restrict__ sm) {
    __shared__ int lds[1024];
    __shared__ float sm3[192];
    int tid = threadIdx.x;
    int v0 = cnt[tid * 4 + 0];
    int v1 = cnt[tid * 4 + 1];
    int v2 = cnt[tid * 4 + 2];
    int v3 = cnt[tid * 4 + 3];
    int p0 = (v0 + 7) & ~7, p1 = (v1 + 7) & ~7, p2 = (v2 + 7) & ~7, p3 = (v3 + 7) & ~7;
    int s = p0 + p1 + p2 + p3;
    lds[tid] = s;
    __syncthreads();
    for (int off = 1; off < 1024; off <<= 1) {
        int t = (tid >= off) ? lds[tid - off] : 0;
        __syncthreads();
        lds[tid] += t;
        __syncthreads();
    }
    int e = (tid > 0) ? lds[tid - 1] : 0;
    int idx = tid * 4;
    row_start[idx + 0] = e; cursor[idx + 0] = e; dis[idx + 0] = rsqrtf((float)(v0 + 1)); e += p0;
    row_start[idx + 1] = e; cursor[idx + 1] = e; dis[idx + 1] = rsqrtf((float)(v1 + 1)); e += p1;
    row_start[idx + 2] = e; cursor[idx + 2] = e; dis[idx + 2] = rsqrtf((float)(v2 + 1)); e += p2;
    row_start[idx + 3] = e; cursor[idx + 3] = e; dis[idx + 3] = rsqrtf((float)(v3 + 1)); e += p3;
    if (tid == 1023) row_start[4096] = lds[1023];
    // ---- small matrices: M3 = W1 @ w_out[8:72] (64x3); then 3x3 collapse ----
    if (tid < 192) {
        int f = tid / 3, c = tid - 3 * (tid / 3);
        float acc = 0.f;
        for (int g = 0; g < 64; ++g) acc += W1[f * 64 + g] * w_out[(8 + g) * 3 + c];
        sm3[tid] = acc;
    }
    __syncthreads();
    if (tid < 9) {
        int k = tid / 3, c = tid - 3 * (tid / 3);
        float acc = 0.f;
        for (int f = 0; f < 64; ++f) acc += W0[k * 64 + f] * sm3[f * 3 + c];
        sm[tid] = acc;
    } else if (tid < 12) {
        int c = tid - 9;
        float acc = 0.f;
        for (int f = 0; f < 64; ++f) acc += b0[f] * sm3[f * 3 + c];
        sm[tid] = acc;
    } else if (tid < 15) {
        int c = tid - 12;
        float acc = 0.f;
        for (int g = 0; g < 64; ++g) acc += b1[g] * w_out[(8 + g) * 3 + c];
        sm[tid] = acc;
    }
}

__global__ void k_padfill(int* __restrict__ csr) {
    int i = blockIdx.x * 256 + threadIdx.x;
    csr[i] = NN;  // sentinel -> zero feature block
}

__global__ void k_fill(const int* __restrict__ src, const int* __restrict__ dst,
                       int* __restrict__ cursor, int* __restrict__ csr_src) {
    int i = blockIdx.x * 256 + threadIdx.x;
    if (i < EE) {
        int d = dst[i];
        int p = atomicAdd(&cursor[d], 1);
        csr_src[p] = src[i];
    }
}

// ---------------- v0[n][l] = dis[n]*pos[b][n*3+c], l = b*4+c (c<3), 256B/node ----------------

__global__ void k_v0(const float* __restrict__ pos, const float* __restrict__ dis,
                     float* __restrict__ v0) {
    int tid = threadIdx.x;
    int n = blockIdx.x * 4 + (tid >> 6);
    int l = tid & 63;
    if (n > NN) return;
    if (n == NN) { v0[(size_t)NN * 64 + l] = 0.f; return; }
    int b = l >> 2, c = l & 3;
    float val = 0.f;
    if (c < 3) val = dis[n] * pos[(size_t)b * (NN * 3) + n * 3 + c];
    v0[(size_t)n * 64 + l] = val;
}

// ---------------- gather pass 1: P = v0[n] + sum_in v0[s]; u = dis^2*(P@W0M3)+dis*b0M3 ----------------
// wave per node, no __syncthreads (wave-private LDS); 1 dword gather per edge per wave.

__global__ __launch_bounds__(256) void k_gath1(const float* __restrict__ v0,
                                               const int* __restrict__ row_start,
                                               const int* __restrict__ csr,
                                               const float* __restrict__ dis,
                                               const float* __restrict__ sm,
                                               float* __restrict__ u) {
    __shared__ int sidx[4][128];
    __shared__ float sP[4][64];
    int w = threadIdx.x >> 6;
    int l = threadIdx.x & 63;
    int n = blockIdx.x * 4 + w;
    if (n > NN) return;
    if (n == NN) { u[(size_t)NN * 64 + l] = 0.f; return; }
    int rs = row_start[n];
    int deg = row_start[n + 1] - rs;  // multiple of 8
    if (l < deg) sidx[w][l] = csr[rs + l];
    if (64 + l < deg && 64 + l < 128) sidx[w][64 + l] = csr[rs + 64 + l];
    float acc = v0[(size_t)n * 64 + l];
    int degc = deg < 128 ? deg : 128;
    int nch = degc >> 3;
    float A[8], B[8];
    if (nch > 0) {
#pragma unroll
        for (int i = 0; i < 8; ++i) A[i] = v0[(size_t)sidx[w][i] * 64 + l];
    }
    for (int c = 0; c < nch; ++c) {
        if (c + 1 < nch) {
            int base = (c + 1) * 8;
#pragma unroll
            for (int i = 0; i < 8; ++i) B[i] = v0[(size_t)sidx[w][base + i] * 64 + l];
        }
#pragma unroll
        for (int i = 0; i < 8; ++i) acc += A[i];
        if (c + 1 < nch) {
#pragma unroll
            for (int i = 0; i < 8; ++i) A[i] = B[i];
        }
    }
    for (int e = 128; e < deg; ++e) acc += v0[(size_t)csr[rs + e] * 64 + l];
    sP[w][l] = acc;
    int base = l & ~3;
    float P0 = sP[w][base + 0], P1 = sP[w][base + 1], P2 = sP[w][base + 2];
    int c = l & 3;
    float d = dis[n];
    float uu = 0.f;
    if (c < 3)
        uu = d * d * (P0 * sm[c] + P1 * sm[3 + c] + P2 * sm[6 + c]) + d * sm[9 + c];
    u[(size_t)n * 64 + l] = uu;
}

// ---------------- gather pass 2: h1y = dis[n]*(u[n]+sum_in u[s]) + b1Wh ----------------

__global__ __launch_bounds__(256) void k_gath2(const float* __restrict__ u,
                                               const int* __restrict__ row_start,
                                               const int* __restrict__ csr,
                                               const float* __restrict__ dis,
                                               const float* __restrict__ sm,
                                               float* __restrict__ h1y) {
    __shared__ int sidx[4][128];
    int w = threadIdx.x >> 6;
    int l = threadIdx.x & 63;
    int n = blockIdx.x * 4 + w;
    if (n >= NN) return;
    int rs = row_start[n];
    int deg = row_start[n + 1] - rs;
    if (l < deg) sidx[w][l] = csr[rs + l];
    if (64 + l < deg && 64 + l < 128) sidx[w][64 + l] = csr[rs + 64 + l];
    float acc = u[(size_t)n * 64 + l];
    int degc = deg < 128 ? deg : 128;
    int nch = degc >> 3;
    float A[8], B[8];
    if (nch > 0) {
#pragma unroll
        for (int i = 0; i < 8; ++i) A[i] = u[(size_t)sidx[w][i] * 64 + l];
    }
    for (int c = 0; c < nch; ++c) {
        if (c + 1 < nch) {
            int base = (c + 1) * 8;
#pragma unroll
            for (int i = 0; i < 8; ++i) B[i] = u[(size_t)sidx[w][base + i] * 64 + l];
        }
#pragma unroll
        for (int i = 0; i < 8; ++i) acc += A[i];
        if (c + 1 < nch) {
#pragma unroll
            for (int i = 0; i < 8; ++i) A[i] = B[i];
        }
    }
    for (int e = 128; e < deg; ++e) acc += u[(size_t)csr[rs + e] * 64 + l];
    int c = l & 3;
    float val = dis[n] * acc + ((c < 3) ? sm[12 + c] : 0.f);
    h1y[(size_t)n * 64 + l] = val;
}

// ---------------- GRUCell: 128 blocks = 16 b x 8 jblk ----------------

__global__ void k_gru(const float* __restrict__ x, const float* __restrict__ hidden,
                      const float* __restrict__ w_ih, const float* __restrict__ b_ih,
                      const float* __restrict__ w_hh, const float* __restrict__ b_hh,
                      float* __restrict__ nh_out, float* __restrict__ nh_ws) {
    __shared__ float s_x[128];
    __shared__ float s_h[512];
    __shared__ float s_p[4 * 64 * 7];
    int tid = threadIdx.x;
    int b = blockIdx.x >> 3;
    int jblk = blockIdx.x & 7;
    if (tid < 128) s_x[tid] = x[b * IN_F + tid];
    for (int i = tid; i < 512; i += 256) s_h[i] = hidden[b * HH + i];
    __syncthreads();
    int jloc = tid & 63;
    int ks = tid >> 6;  // 0..3
    int j = jblk * 64 + jloc;
    float air = 0.f, aiz = 0.f, ain = 0.f, ahr = 0.f, ahz = 0.f, ahn = 0.f;
    {
        const float4* wi0 = (const float4*)(w_ih + (size_t)j * IN_F + ks * 32);
        const float4* wi1 = (const float4*)(w_ih + (size_t)(HH + j) * IN_F + ks * 32);
        const float4* wi2 = (const float4*)(w_ih + (size_t)(2 * HH + j) * IN_F + ks * 32);
        const float4* xs = (const float4*)(s_x + ks * 32);
#pragma unroll
        for (int i = 0; i < 8; ++i) {
            float4 xv = xs[i];
            float4 a = wi0[i], c = wi1[i], d = wi2[i];
            air += xv.x * a.x + xv.y * a.y + xv.z * a.z + xv.w * a.w;
            aiz += xv.x * c.x + xv.y * c.y + xv.z * c.z + xv.w * c.w;
            ain += xv.x * d.x + xv.y * d.y + xv.z * d.z + xv.w * d.w;
        }
    }
    {
        const float4* wh0 = (const float4*)(w_hh + (size_t)j * HH + ks * 128);
        const float4* wh1 = (const float4*)(w_hh + (size_t)(HH + j) * HH + ks * 128);
        const float4* wh2 = (const float4*)(w_hh + (size_t)(2 * HH + j) * HH + ks * 128);
        const float4* hs = (const float4*)(s_h + ks * 128);
#pragma unroll 8
        for (int i = 0; i < 32; ++i) {
            float4 hv = hs[i];
            float4 a = wh0[i], c = wh1[i], d = wh2[i];
            ahr += hv.x * a.x + hv.y * a.y + hv.z * a.z + hv.w * a.w;
            ahz += hv.x * c.x + hv.y * c.y + hv.z * c.z + hv.w * c.w;
            ahn += hv.x * d.x + hv.y * d.y + hv.z * d.z + hv.w * d.w;
        }
    }
    float* pp = s_p + (ks * 64 + jloc) * 7;
    pp[0] = air; pp[1] = aiz; pp[2] = ain; pp[3] = ahr; pp[4] = ahz; pp[5] = ahn;
    __syncthreads();
    if (tid < 64) {
        int jj = jblk * 64 + tid;
        float v0 = 0.f, v1 = 0.f, v2 = 0.f, v3 = 0.f, v4 = 0.f, v5 = 0.f;
#pragma unroll
        for (int s = 0; s < 4; ++s) {
            const float* q = s_p + (s * 64 + tid) * 7;
            v0 += q[0]; v1 += q[1]; v2 += q[2]; v3 += q[3]; v4 += q[4]; v5 += q[5];
        }
        float ir = v0 + b_ih[jj], iz = v1 + b_ih[HH + jj], inn = v2 + b_ih[2 * HH + jj];
        float hr = v3 + b_hh[jj], hz = v4 + b_hh[HH + jj], hn = v5 + b_hh[2 * HH + jj];
        float r = 1.f / (1.f + expf(-(ir + hr)));
        float z = 1.f / (1.f + expf(-(iz + hz)));
        float nn = tanhf(inn + r * hn);
        float hprev = s_h[jj];
        float nh = (1.f - z) * nn + z * hprev;
        nh_out[b * HH + jj] = nh;
        nh_ws[b * HH + jj] = nh;
    }
}

// ---------------- MLP layer 1 ----------------

__global__ void k_mlp1(const float* __restrict__ nh, const float* __restrict__ w1,
                       const float* __restrict__ b1, const float* __restrict__ alpha1,
                       const float* __restrict__ g1, const float* __restrict__ bt1,
                       const float* __restrict__ mu1, const float* __restrict__ var1,
                       float* __restrict__ m1) {
    __shared__ float s_nh[512];
    __shared__ float s_p[4 * 64];
    int tid = threadIdx.x;
    int b = blockIdx.x >> 3;
    int jblk = blockIdx.x & 7;
    for (int i = tid; i < 512; i += 256) s_nh[i] = nh[b * HH + i];
    __syncthreads();
    int jloc = tid & 63;
    int ks = tid >> 6;
    int j = jblk * 64 + jloc;
    const float* wp = w1 + (size_t)(ks * 128) * D1 + j;
    float acc = 0.f;
#pragma unroll 4
    for (int k0 = 0; k0 < 128; k0 += 4) {
        float w0 = wp[0], w1v = wp[D1], w2v = wp[2 * D1], w3v = wp[3 * D1];
        float4 mv = *(const float4*)&s_nh[ks * 128 + k0];
        acc += mv.x * w0 + mv.y * w1v + mv.z * w2v + mv.w * w3v;
        wp += 4 * D1;
    }
    s_p[ks * 64 + jloc] = acc;
    __syncthreads();
    if (tid < 64) {
        int jj = jblk * 64 + tid;
        float v = s_p[tid] + s_p[64 + tid] + s_p[128 + tid] + s_p[192 + tid];
        v += b1[jj];
        float al = alpha1[jj];
        v = v > 0.f ? v : al * v;
        float iv = rsqrtf(var1[jj] + EPSV);
        m1[b * D1 + jj] = g1[jj] * (v - mu1[jj]) * iv + bt1[jj];
    }
}

// ---------------- MLP layer 2: 512 blocks = 64 jt (512 cols) x 8 ok (64 k) ----------------

__global__ void k_mlp2(const float* __restrict__ m1, const float* __restrict__ w2,
                       float* __restrict__ part) {
    __shared__ float s_m1[16 * 64];
    int tid = threadIdx.x;
    int jt = blockIdx.x >> 3;
    int ok = blockIdx.x & 7;
    {
        int b = tid >> 4, kg = tid & 15;
        *(float4*)&s_m1[b * 64 + kg * 4] = *(const float4*)(m1 + b * 512 + ok * 64 + kg * 4);
    }
    __syncthreads();
    int j = jt * 512 + tid * 2;
    const float* wp = w2 + (size_t)(ok * 64) * D2 + j;
    float2 wb0 = *(const float2*)(wp + 0 * (size_t)D2);
    float2 wb1 = *(const float2*)(wp + 1 * (size_t)D2);
    float2 wb2 = *(const float2*)(wp + 2 * (size_t)D2);
    float2 wb3 = *(const float2*)(wp + 3 * (size_t)D2);
    float acc0[16], acc1[16];
#pragma unroll
    for (int b = 0; b < 16; ++b) { acc0[b] = 0.f; acc1[b] = 0.f; }
    for (int k4 = 0; k4 < 64; k4 += 4) {
        float2 c0 = wb0, c1 = wb1, c2 = wb2, c3 = wb3;
        int kp = (k4 + 4 < 64) ? k4 + 4 : 0;
        wb0 = *(const float2*)(wp + (size_t)(kp + 0) * D2);
        wb1 = *(const float2*)(wp + (size_t)(kp + 1) * D2);
        wb2 = *(const float2*)(wp + (size_t)(kp + 2) * D2);
        wb3 = *(const float2*)(wp + (size_t)(kp + 3) * D2);
#pragma unroll
        for (int b = 0; b < 16; ++b) {
            float2 p01 = *(const float2*)&s_m1[b * 64 + k4];
            float2 p23 = *(const float2*)&s_m1[b * 64 + k4 + 2];
            acc0[b] += p01.x * c0.x + p01.y * c1.x + p23.x * c2.x + p23.y * c3.x;
            acc1[b] += p01.x * c0.y + p01.y * c1.y + p23.x * c2.y + p23.y * c3.y;
        }
    }
    float* pb = part + (size_t)(ok * 16) * D2 + j;
#pragma unroll
    for (int b = 0; b < 16; ++b) {
        *(float2*)(pb + (size_t)b * D2) = make_float2(acc0[b], acc1[b]);
    }
}

// ---------------- Output head: mlp2-reduce + bias/PReLU/BN + gru@w_out + h1y ----------------

__global__ void k_out(const float* __restrict__ part, const float* __restrict__ h1y,
                      const float* __restrict__ b2, const float* __restrict__ alpha2,
                      const float* __restrict__ g2, const float* __restrict__ bt2,
                      const float* __restrict__ mu2, const float* __restrict__ var2,
                      const float* __restrict__ w_out, const float* __restrict__ b_out,
                      float* __restrict__ y) {
    __shared__ float sw[24];
    __shared__ float sb[3];
    int tid = threadIdx.x;
    if (tid < 24) sw[tid] = w_out[tid];
    if (tid < 3) sb[tid] = b_out[tid];
    __syncthreads();
    int t = blockIdx.x * 256 + tid;
    int n = t & (NN - 1);
    int b = t >> 12;
    int j0 = n * 8;
    float4 sA = make_float4(0.f, 0.f, 0.f, 0.f);
    float4 sB = make_float4(0.f, 0.f, 0.f, 0.f);
#pragma unroll
    for (int ok = 0; ok < 8; ++ok) {
        const float* pp = part + (size_t)(ok * 16 + b) * D2 + j0;
        float4 pa = *(const float4*)pp;
        float4 pb = *(const float4*)(pp + 4);
        sA.x += pa.x; sA.y += pa.y; sA.z += pa.z; sA.w += pa.w;
        sB.x += pb.x; sB.y += pb.y; sB.z += pb.z; sB.w += pb.w;
    }
    float raw[8] = {sA.x, sA.y, sA.z, sA.w, sB.x, sB.y, sB.z, sB.w};
    float4 bja = *(const float4*)(b2 + j0),    bjb = *(const float4*)(b2 + j0 + 4);
    float4 ala = *(const float4*)(alpha2 + j0), alb = *(const float4*)(alpha2 + j0 + 4);
    float4 gaa = *(const float4*)(g2 + j0),    gab = *(const float4*)(g2 + j0 + 4);
    float4 bea = *(const float4*)(bt2 + j0),   beb = *(const float4*)(bt2 + j0 + 4);
    float4 mua = *(const float4*)(mu2 + j0),   mub = *(const float4*)(mu2 + j0 + 4);
    float4 vaa = *(const float4*)(var2 + j0),  vab = *(const float4*)(var2 + j0 + 4);
    float bj[8] = {bja.x, bja.y, bja.z, bja.w, bjb.x, bjb.y, bjb.z, bjb.w};
    float al[8] = {ala.x, ala.y, ala.z, ala.w, alb.x, alb.y, alb.z, alb.w};
    float ga[8] = {gaa.x, gaa.y, gaa.z, gaa.w, gab.x, gab.y, gab.z, gab.w};
    float be[8] = {bea.x, bea.y, bea.z, bea.w, beb.x, beb.y, beb.z, beb.w};
    float mu[8] = {mua.x, mua.y, mua.z, mua.w, mub.x, mub.y, mub.z, mub.w};
    float va[8] = {vaa.x, vaa.y, vaa.z, vaa.w, vab.x, vab.y, vab.z, vab.w};
    float4 hv = *(const float4*)(h1y + (size_t)n * 64 + b * 4);
    float y0 = sb[0] + hv.x, y1 = sb[1] + hv.y, y2 = sb[2] + hv.z;
#pragma unroll
    for (int g = 0; g < 8; ++g) {
        float v = raw[g] + bj[g];
        v = v > 0.f ? v : al[g] * v;
        v = ga[g] * (v - mu[g]) * rsqrtf(va[g] + EPSV) + be[g];
        y0 += v * sw[g * 3 + 0];
        y1 += v * sw[g * 3 + 1];
        y2 += v * sw[g * 3 + 2];
    }
    float* yo = y + (size_t)b * (NN * 3) + n * 3;
    yo[0] = y0;
    yo[1] = y1;
    yo[2] = y2;
}

// ---------------- launcher ----------------

extern "C" void kernel_launch(void* const* d_in, const int* in_sizes, int n_in,
                              void* d_out, int out_size, void* d_ws, size_t ws_size,
                              hipStream_t stream) {
    const float* x      = (const float*)d_in[0];
    const float* pos    = (const float*)d_in[1];
    const float* hidden = (const float*)d_in[2];
    const int*   ei     = (const int*)d_in[3];
    const float* W0     = (const float*)d_in[4];
    const float* b0     = (const float*)d_in[5];
    const float* W1     = (const float*)d_in[6];
    const float* b1     = (const float*)d_in[7];
    const float* w_ih   = (const float*)d_in[8];
    const float* b_ih   = (const float*)d_in[9];
    const float* w_hh   = (const float*)d_in[10];
    const float* b_hh   = (const float*)d_in[11];
    const float* mlp_w1 = (const float*)d_in[12];
    const float* mlp_b1 = (const float*)d_in[13];
    const float* alpha1 = (const float*)d_in[14];
    const float* bn1g   = (const float*)d_in[15];
    const float* bn1b   = (const float*)d_in[16];
    const float* bn1m   = (const float*)d_in[17];
    const float* bn1v   = (const float*)d_in[18];
    const float* mlp_w2 = (const float*)d_in[19];
    const float* mlp_b2 = (const float*)d_in[20];
    const float* alpha2 = (const float*)d_in[21];
    const float* bn2g   = (const float*)d_in[22];
    const float* bn2b   = (const float*)d_in[23];
    const float* bn2m   = (const float*)d_in[24];
    const float* bn2v   = (const float*)d_in[25];
    const float* w_out  = (const float*)d_in[26];
    const float* b_out  = (const float*)d_in[27];

    float* out = (float*)d_out;
    float* ws = (float*)d_ws;

    // workspace layout (float offsets)
    float* v0   = ws;                  // 4097*64 = 262208
    float* u    = ws + 262208;         // 262208
    float* h1y  = ws + 524416;         // 4096*64 = 262144
    float* part = ws + 786560;         // 8*16*32768 = 4194304
    float* nh   = ws + 4980864;        // 8192
    float* m1s  = ws + 4989056;        // 8192
    float* dis  = ws + 4997248;        // 4096
    float* sm   = ws + 5001344;        // 16
    int* wsi       = (int*)(ws + 5001360);
    int* cnt       = wsi;                       // 4096
    int* row_start = wsi + 4096;                // 4097
    int* cursor    = wsi + 4096 + 4097;         // 4096
    int* csr       = wsi + 4096 + 4097 + 4096;  // PADMAX

    const int* srcp = ei;
    const int* dstp = ei + EE;

    hipMemsetAsync(cnt, 0, 4096 * sizeof(int), stream);
    k_hist<<<EE / 256, 256, 0, stream>>>(dstp, cnt);
    k_scan<<<1, 1024, 0, stream>>>(cnt, row_start, cursor, dis, W0, b0, W1, b1, w_out, sm);
    k_padfill<<<PADMAX / 256, 256, 0, stream>>>(csr);
    k_fill<<<EE / 256, 256, 0, stream>>>(srcp, dstp, cursor, csr);
    k_v0<<<1025, 256, 0, stream>>>(pos, dis, v0);
    k_gath1<<<1025, 256, 0, stream>>>(v0, row_start, csr, dis, sm, u);
    k_gath2<<<1024, 256, 0, stream>>>(u, row_start, csr, dis, sm, h1y);
    k_gru<<<128, 256, 0, stream>>>(x, hidden, w_ih, b_ih, w_hh, b_hh, out + BB * NN * 3, nh);
    k_mlp1<<<128, 256, 0, stream>>>(nh, mlp_w1, mlp_b1, alpha1, bn1g, bn1b, bn1m, bn1v, m1s);
    k_mlp2<<<512, 256, 0, stream>>>(m1s, mlp_w2, part);
    k_out<<<(BB * NN) / 256, 256, 0, stream>>>(part, h1y, mlp_b2, alpha2, bn2g, bn2b, bn2m,
                                               bn2v, w_out, b_out, out);
}

// Round 9
// 93.327 us; speedup vs baseline: 1.8337x; 1.0171x over previous
//
#include <hip/hip_runtime.h>
#include <math.h>

#define BB 16
#define NN 4096
#define EE 65536
#define IN_F 128
#define HH 512
#define D1 512
#define D2 32768
#define EPSV 1e-5f
#define PADMAX 94208  // EE + NN*7 worst-case padded CSR

// ---------------- GCN support: init / histogram / scan(+small-matrix precompute) / fill ----------------

// fills csr with sentinel AND zeroes cnt (replaces hipMemsetAsync: a 16KB
// in-graph fillBuffer dispatch measured ~40us -- pure-write kernel instead)
__global__ void k_init(int* __restrict__ csr, int* __restrict__ cnt) {
    int i = blockIdx.x * 256 + threadIdx.x;
    csr[i] = NN;  // sentinel -> zero feature block
    if (i < 4096) cnt[i] = 0;
}

__global__ void k_hist(const int* __restrict__ dst, int* __restrict__ cnt) {
    int i = blockIdx.x * 256 + threadIdx.x;
    if (i < EE) atomicAdd(&cnt[dst[i]], 1);
}

// prefix-sum of PADDED counts (rows padded to multiple of 8) + dis + collapsed small matrices
// sm layout: [0..8] W0M3 (3x3 row-major k*3+c), [9..11] b0@M3, [12..14] b1@Wh
__global__ void k_scan(const int* __restrict__ cnt, int* __restrict__ row_start,
                       int* __restrict__ cursor, float* __restrict__ dis,
                       const float* __restrict__ W0, const float* __restrict__ b0,
                       const float* __restrict__ W1, const float* __restrict__ b1,
                       const float* __restrict__ w_out, float* __restrict__ sm) {
    __shared__ int lds[1024];
    __shared__ float sm3[192];
    int tid = threadIdx.x;
    int v0 = cnt[tid * 4 + 0];
    int v1 = cnt[tid * 4 + 1];
    int v2 = cnt[tid * 4 + 2];
    int v3 = cnt[tid * 4 + 3];
    int p0 = (v0 + 7) & ~7, p1 = (v1 + 7) & ~7, p2 = (v2 + 7) & ~7, p3 = (v3 + 7) & ~7;
    int s = p0 + p1 + p2 + p3;
    lds[tid] = s;
    __syncthreads();
    for (int off = 1; off < 1024; off <<= 1) {
        int t = (tid >= off) ? lds[tid - off] : 0;
        __syncthreads();
        lds[tid] += t;
        __syncthreads();
    }
    int e = (tid > 0) ? lds[tid - 1] : 0;
    int idx = tid * 4;
    row_start[idx + 0] = e; cursor[idx + 0] = e; dis[idx + 0] = rsqrtf((float)(v0 + 1)); e += p0;
    row_start[idx + 1] = e; cursor[idx + 1] = e; dis[idx + 1] = rsqrtf((float)(v1 + 1)); e += p1;
    row_start[idx + 2] = e; cursor[idx + 2] = e; dis[idx + 2] = rsqrtf((float)(v2 + 1)); e += p2;
    row_start[idx + 3] = e; cursor[idx + 3] = e; dis[idx + 3] = rsqrtf((float)(v3 + 1)); e += p3;
    if (tid == 1023) row_start[4096] = lds[1023];
    // ---- small matrices: M3 = W1 @ w_out[8:72] (64x3); then 3x3 collapse ----
    if (tid < 192) {
        int f = tid / 3, c = tid - 3 * (tid / 3);
        float acc = 0.f;
        for (int g = 0; g < 64; ++g) acc += W1[f * 64 + g] * w_out[(8 + g) * 3 + c];
        sm3[tid] = acc;
    }
    __syncthreads();
    if (tid < 9) {
        int k = tid / 3, c = tid - 3 * (tid / 3);
        float acc = 0.f;
        for (int f = 0; f < 64; ++f) acc += W0[k * 64 + f] * sm3[f * 3 + c];
        sm[tid] = acc;
    } else if (tid < 12) {
        int c = tid - 9;
        float acc = 0.f;
        for (int f = 0; f < 64; ++f) acc += b0[f] * sm3[f * 3 + c];
        sm[tid] = acc;
    } else if (tid < 15) {
        int c = tid - 12;
        float acc = 0.f;
        for (int g = 0; g < 64; ++g) acc += b1[g] * w_out[(8 + g) * 3 + c];
        sm[tid] = acc;
    }
}

__global__ void k_fill(const int* __restrict__ src, const int* __restrict__ dst,
                       int* __restrict__ cursor, int* __restrict__ csr_src) {
    int i = blockIdx.x * 256 + threadIdx.x;
    if (i < EE) {
        int d = dst[i];
        int p = atomicAdd(&cursor[d], 1);
        csr_src[p] = src[i];
    }
}

// ---------------- v0[n][l] = dis[n]*pos[b][n*3+c], l = b*4+c (c<3), 256B/node ----------------

__global__ void k_v0(const float* __restrict__ pos, const float* __restrict__ dis,
                     float* __restrict__ v0) {
    int tid = threadIdx.x;
    int n = blockIdx.x * 4 + (tid >> 6);
    int l = tid & 63;
    if (n > NN) return;
    if (n == NN) { v0[(size_t)NN * 64 + l] = 0.f; return; }
    int b = l >> 2, c = l & 3;
    float val = 0.f;
    if (c < 3) val = dis[n] * pos[(size_t)b * (NN * 3) + n * 3 + c];
    v0[(size_t)n * 64 + l] = val;
}

// ---------------- gather pass 1: P = v0[n] + sum_in v0[s]; u = dis^2*(P@W0M3)+dis*b0M3 ----------------
// wave per node, no __syncthreads (wave-private LDS); 256B gather per edge per wave.

__global__ __launch_bounds__(256) void k_gath1(const float* __restrict__ v0,
                                               const int* __restrict__ row_start,
                                               const int* __restrict__ csr,
                                               const float* __restrict__ dis,
                                               const float* __restrict__ sm,
                                               float* __restrict__ u) {
    __shared__ int sidx[4][128];
    __shared__ float sP[4][64];
    int w = threadIdx.x >> 6;
    int l = threadIdx.x & 63;
    int n = blockIdx.x * 4 + w;
    if (n > NN) return;
    if (n == NN) { u[(size_t)NN * 64 + l] = 0.f; return; }
    int rs = row_start[n];
    int deg = row_start[n + 1] - rs;  // multiple of 8
    if (l < deg) sidx[w][l] = csr[rs + l];
    if (64 + l < deg && 64 + l < 128) sidx[w][64 + l] = csr[rs + 64 + l];
    float acc = v0[(size_t)n * 64 + l];
    int degc = deg < 128 ? deg : 128;
    int nch = degc >> 3;
    float A[8], B[8];
    if (nch > 0) {
#pragma unroll
        for (int i = 0; i < 8; ++i) A[i] = v0[(size_t)sidx[w][i] * 64 + l];
    }
    for (int c = 0; c < nch; ++c) {
        if (c + 1 < nch) {
            int base = (c + 1) * 8;
#pragma unroll
            for (int i = 0; i < 8; ++i) B[i] = v0[(size_t)sidx[w][base + i] * 64 + l];
        }
#pragma unroll
        for (int i = 0; i < 8; ++i) acc += A[i];
        if (c + 1 < nch) {
#pragma unroll
            for (int i = 0; i < 8; ++i) A[i] = B[i];
        }
    }
    for (int e = 128; e < deg; ++e) acc += v0[(size_t)csr[rs + e] * 64 + l];
    sP[w][l] = acc;
    int base = l & ~3;
    float P0 = sP[w][base + 0], P1 = sP[w][base + 1], P2 = sP[w][base + 2];
    int c = l & 3;
    float d = dis[n];
    float uu = 0.f;
    if (c < 3)
        uu = d * d * (P0 * sm[c] + P1 * sm[3 + c] + P2 * sm[6 + c]) + d * sm[9 + c];
    u[(size_t)n * 64 + l] = uu;
}

// ---------------- gather pass 2: h1y = dis[n]*(u[n]+sum_in u[s]) + b1Wh ----------------

__global__ __launch_bounds__(256) void k_gath2(const float* __restrict__ u,
                                               const int* __restrict__ row_start,
                                               const int* __restrict__ csr,
                                               const float* __restrict__ dis,
                                               const float* __restrict__ sm,
                                               float* __restrict__ h1y) {
    __shared__ int sidx[4][128];
    int w = threadIdx.x >> 6;
    int l = threadIdx.x & 63;
    int n = blockIdx.x * 4 + w;
    if (n >= NN) return;
    int rs = row_start[n];
    int deg = row_start[n + 1] - rs;
    if (l < deg) sidx[w][l] = csr[rs + l];
    if (64 + l < deg && 64 + l < 128) sidx[w][64 + l] = csr[rs + 64 + l];
    float acc = u[(size_t)n * 64 + l];
    int degc = deg < 128 ? deg : 128;
    int nch = degc >> 3;
    float A[8], B[8];
    if (nch > 0) {
#pragma unroll
        for (int i = 0; i < 8; ++i) A[i] = u[(size_t)sidx[w][i] * 64 + l];
    }
    for (int c = 0; c < nch; ++c) {
        if (c + 1 < nch) {
            int base = (c + 1) * 8;
#pragma unroll
            for (int i = 0; i < 8; ++i) B[i] = u[(size_t)sidx[w][base + i] * 64 + l];
        }
#pragma unroll
        for (int i = 0; i < 8; ++i) acc += A[i];
        if (c + 1 < nch) {
#pragma unroll
            for (int i = 0; i < 8; ++i) A[i] = B[i];
        }
    }
    for (int e = 128; e < deg; ++e) acc += u[(size_t)csr[rs + e] * 64 + l];
    int c = l & 3;
    float val = dis[n] * acc + ((c < 3) ? sm[12 + c] : 0.f);
    h1y[(size_t)n * 64 + l] = val;
}

// ---------------- GRUCell: 128 blocks = 16 b x 8 jblk ----------------

__global__ void k_gru(const float* __restrict__ x, const float* __restrict__ hidden,
                      const float* __restrict__ w_ih, const float* __restrict__ b_ih,
                      const float* __restrict__ w_hh, const float* __restrict__ b_hh,
                      float* __restrict__ nh_out, float* __restrict__ nh_ws) {
    __shared__ float s_x[128];
    __shared__ float s_h[512];
    __shared__ float s_p[4 * 64 * 7];
    int tid = threadIdx.x;
    int b = blockIdx.x >> 3;
    int jblk = blockIdx.x & 7;
    if (tid < 128) s_x[tid] = x[b * IN_F + tid];
    for (int i = tid; i < 512; i += 256) s_h[i] = hidden[b * HH + i];
    __syncthreads();
    int jloc = tid & 63;
    int ks = tid >> 6;  // 0..3
    int j = jblk * 64 + jloc;
    float air = 0.f, aiz = 0.f, ain = 0.f, ahr = 0.f, ahz = 0.f, ahn = 0.f;
    {
        const float4* wi0 = (const float4*)(w_ih + (size_t)j * IN_F + ks * 32);
        const float4* wi1 = (const float4*)(w_ih + (size_t)(HH + j) * IN_F + ks * 32);
        const float4* wi2 = (const float4*)(w_ih + (size_t)(2 * HH + j) * IN_F + ks * 32);
        const float4* xs = (const float4*)(s_x + ks * 32);
#pragma unroll
        for (int i = 0; i < 8; ++i) {
            float4 xv = xs[i];
            float4 a = wi0[i], c = wi1[i], d = wi2[i];
            air += xv.x * a.x + xv.y * a.y + xv.z * a.z + xv.w * a.w;
            aiz += xv.x * c.x + xv.y * c.y + xv.z * c.z + xv.w * c.w;
            ain += xv.x * d.x + xv.y * d.y + xv.z * d.z + xv.w * d.w;
        }
    }
    {
        const float4* wh0 = (const float4*)(w_hh + (size_t)j * HH + ks * 128);
        const float4* wh1 = (const float4*)(w_hh + (size_t)(HH + j) * HH + ks * 128);
        const float4* wh2 = (const float4*)(w_hh + (size_t)(2 * HH + j) * HH + ks * 128);
        const float4* hs = (const float4*)(s_h + ks * 128);
#pragma unroll 8
        for (int i = 0; i < 32; ++i) {
            float4 hv = hs[i];
            float4 a = wh0[i], c = wh1[i], d = wh2[i];
            ahr += hv.x * a.x + hv.y * a.y + hv.z * a.z + hv.w * a.w;
            ahz += hv.x * c.x + hv.y * c.y + hv.z * c.z + hv.w * c.w;
            ahn += hv.x * d.x + hv.y * d.y + hv.z * d.z + hv.w * d.w;
        }
    }
    float* pp = s_p + (ks * 64 + jloc) * 7;
    pp[0] = air; pp[1] = aiz; pp[2] = ain; pp[3] = ahr; pp[4] = ahz; pp[5] = ahn;
    __syncthreads();
    if (tid < 64) {
        int jj = jblk * 64 + tid;
        float v0 = 0.f, v1 = 0.f, v2 = 0.f, v3 = 0.f, v4 = 0.f, v5 = 0.f;
#pragma unroll
        for (int s = 0; s < 4; ++s) {
            const float* q = s_p + (s * 64 + tid) * 7;
            v0 += q[0]; v1 += q[1]; v2 += q[2]; v3 += q[3]; v4 += q[4]; v5 += q[5];
        }
        float ir = v0 + b_ih[jj], iz = v1 + b_ih[HH + jj], inn = v2 + b_ih[2 * HH + jj];
        float hr = v3 + b_hh[jj], hz = v4 + b_hh[HH + jj], hn = v5 + b_hh[2 * HH + jj];
        float r = 1.f / (1.f + expf(-(ir + hr)));
        float z = 1.f / (1.f + expf(-(iz + hz)));
        float nn = tanhf(inn + r * hn);
        float hprev = s_h[jj];
        float nh = (1.f - z) * nn + z * hprev;
        nh_out[b * HH + jj] = nh;
        nh_ws[b * HH + jj] = nh;
    }
}

// ---------------- MLP layer 1 ----------------

__global__ void k_mlp1(const float* __restrict__ nh, const float* __restrict__ w1,
                       const float* __restrict__ b1, const float* __restrict__ alpha1,
                       const float* __restrict__ g1, const float* __restrict__ bt1,
                       const float* __restrict__ mu1, const float* __restrict__ var1,
                       float* __restrict__ m1) {
    __shared__ float s_nh[512];
    __shared__ float s_p[4 * 64];
    int tid = threadIdx.x;
    int b = blockIdx.x >> 3;
    int jblk = blockIdx.x & 7;
    for (int i = tid; i < 512; i += 256) s_nh[i] = nh[b * HH + i];
    __syncthreads();
    int jloc = tid & 63;
    int ks = tid >> 6;
    int j = jblk * 64 + jloc;
    const float* wp = w1 + (size_t)(ks * 128) * D1 + j;
    float acc = 0.f;
#pragma unroll 4
    for (int k0 = 0; k0 < 128; k0 += 4) {
        float w0 = wp[0], w1v = wp[D1], w2v = wp[2 * D1], w3v = wp[3 * D1];
        float4 mv = *(const float4*)&s_nh[ks * 128 + k0];
        acc += mv.x * w0 + mv.y * w1v + mv.z * w2v + mv.w * w3v;
        wp += 4 * D1;
    }
    s_p[ks * 64 + jloc] = acc;
    __syncthreads();
    if (tid < 64) {
        int jj = jblk * 64 + tid;
        float v = s_p[tid] + s_p[64 + tid] + s_p[128 + tid] + s_p[192 + tid];
        v += b1[jj];
        float al = alpha1[jj];
        v = v > 0.f ? v : al * v;
        float iv = rsqrtf(var1[jj] + EPSV);
        m1[b * D1 + jj] = g1[jj] * (v - mu1[jj]) * iv + bt1[jj];
    }
}

// ---------------- MLP layer 2: 512 blocks = 64 jt (512 cols) x 8 ok (64 k) ----------------

__global__ void k_mlp2(const float* __restrict__ m1, const float* __restrict__ w2,
                       float* __restrict__ part) {
    __shared__ float s_m1[16 * 64];
    int tid = threadIdx.x;
    int jt = blockIdx.x >> 3;
    int ok = blockIdx.x & 7;
    {
        int b = tid >> 4, kg = tid & 15;
        *(float4*)&s_m1[b * 64 + kg * 4] = *(const float4*)(m1 + b * 512 + ok * 64 + kg * 4);
    }
    __syncthreads();
    int j = jt * 512 + tid * 2;
    const float* wp = w2 + (size_t)(ok * 64) * D2 + j;
    float2 wb0 = *(const float2*)(wp + 0 * (size_t)D2);
    float2 wb1 = *(const float2*)(wp + 1 * (size_t)D2);
    float2 wb2 = *(const float2*)(wp + 2 * (size_t)D2);
    float2 wb3 = *(const float2*)(wp + 3 * (size_t)D2);
    float acc0[16], acc1[16];
#pragma unroll
    for (int b = 0; b < 16; ++b) { acc0[b] = 0.f; acc1[b] = 0.f; }
    for (int k4 = 0; k4 < 64; k4 += 4) {
        float2 c0 = wb0, c1 = wb1, c2 = wb2, c3 = wb3;
        int kp = (k4 + 4 < 64) ? k4 + 4 : 0;
        wb0 = *(const float2*)(wp + (size_t)(kp + 0) * D2);
        wb1 = *(const float2*)(wp + (size_t)(kp + 1) * D2);
        wb2 = *(const float2*)(wp + (size_t)(kp + 2) * D2);
        wb3 = *(const float2*)(wp + (size_t)(kp + 3) * D2);
#pragma unroll
        for (int b = 0; b < 16; ++b) {
            float2 p01 = *(const float2*)&s_m1[b * 64 + k4];
            float2 p23 = *(const float2*)&s_m1[b * 64 + k4 + 2];
            acc0[b] += p01.x * c0.x + p01.y * c1.x + p23.x * c2.x + p23.y * c3.x;
            acc1[b] += p01.x * c0.y + p01.y * c1.y + p23.x * c2.y + p23.y * c3.y;
        }
    }
    float* pb = part + (size_t)(ok * 16) * D2 + j;
#pragma unroll
    for (int b = 0; b < 16; ++b) {
        *(float2*)(pb + (size_t)b * D2) = make_float2(acc0[b], acc1[b]);
    }
}

// ---------------- Output head: mlp2-reduce + bias/PReLU/BN + gru@w_out + h1y ----------------

__global__ void k_out(const float* __restrict__ part, const float* __restrict__ h1y,
                      const float* __restrict__ b2, const float* __restrict__ alpha2,
                      const float* __restrict__ g2, const float* __restrict__ bt2,
                      const float* __restrict__ mu2, const float* __restrict__ var2,
                      const float* __restrict__ w_out, const float* __restrict__ b_out,
                      float* __restrict__ y) {
    __shared__ float sw[24];
    __shared__ float sb[3];
    int tid = threadIdx.x;
    if (tid < 24) sw[tid] = w_out[tid];
    if (tid < 3) sb[tid] = b_out[tid];
    __syncthreads();
    int t = blockIdx.x * 256 + tid;
    int n = t & (NN - 1);
    int b = t >> 12;
    int j0 = n * 8;
    float4 sA = make_float4(0.f, 0.f, 0.f, 0.f);
    float4 sB = make_float4(0.f, 0.f, 0.f, 0.f);
#pragma unroll
    for (int ok = 0; ok < 8; ++ok) {
        const float* pp = part + (size_t)(ok * 16 + b) * D2 + j0;
        float4 pa = *(const float4*)pp;
        float4 pb = *(const float4*)(pp + 4);
        sA.x += pa.x; sA.y += pa.y; sA.z += pa.z; sA.w += pa.w;
        sB.x += pb.x; sB.y += pb.y; sB.z += pb.z; sB.w += pb.w;
    }
    float raw[8] = {sA.x, sA.y, sA.z, sA.w, sB.x, sB.y, sB.z, sB.w};
    float4 bja = *(const float4*)(b2 + j0),    bjb = *(const float4*)(b2 + j0 + 4);
    float4 ala = *(const float4*)(alpha2 + j0), alb = *(const float4*)(alpha2 + j0 + 4);
    float4 gaa = *(const float4*)(g2 + j0),    gab = *(const float4*)(g2 + j0 + 4);
    float4 bea = *(const float4*)(bt2 + j0),   beb = *(const float4*)(bt2 + j0 + 4);
    float4 mua = *(const float4*)(mu2 + j0),   mub = *(const float4*)(mu2 + j0 + 4);
    float4 vaa = *(const float4*)(var2 + j0),  vab = *(const float4*)(var2 + j0 + 4);
    float bj[8] = {bja.x, bja.y, bja.z, bja.w, bjb.x, bjb.y, bjb.z, bjb.w};
    float al[8] = {ala.x, ala.y, ala.z, ala.w, alb.x, alb.y, alb.z, alb.w};
    float ga[8] = {gaa.x, gaa.y, gaa.z, gaa.w, gab.x, gab.y, gab.z, gab.w};
    float be[8] = {bea.x, bea.y, bea.z, bea.w, beb.x, beb.y, beb.z, beb.w};
    float mu[8] = {mua.x, mua.y, mua.z, mua.w, mub.x, mub.y, mub.z, mub.w};
    float va[8] = {vaa.x, vaa.y, vaa.z, vaa.w, vab.x, vab.y, vab.z, vab.w};
    float4 hv = *(const float4*)(h1y + (size_t)n * 64 + b * 4);
    float y0 = sb[0] + hv.x, y1 = sb[1] + hv.y, y2 = sb[2] + hv.z;
#pragma unroll
    for (int g = 0; g < 8; ++g) {
        float v = raw[g] + bj[g];
        v = v > 0.f ? v : al[g] * v;
        v = ga[g] * (v - mu[g]) * rsqrtf(va[g] + EPSV) + be[g];
        y0 += v * sw[g * 3 + 0];
        y1 += v * sw[g * 3 + 1];
        y2 += v * sw[g * 3 + 2];
    }
    float* yo = y + (size_t)b * (NN * 3) + n * 3;
    yo[0] = y0;
    yo[1] = y1;
    yo[2] = y2;
}

// ---------------- launcher ----------------

extern "C" void kernel_launch(void* const* d_in, const int* in_sizes, int n_in,
                              void* d_out, int out_size, void* d_ws, size_t ws_size,
                              hipStream_t stream) {
    const float* x      = (const float*)d_in[0];
    const float* pos    = (const float*)d_in[1];
    const float* hidden = (const float*)d_in[2];
    const int*   ei     = (const int*)d_in[3];
    const float* W0     = (const float*)d_in[4];
    const float* b0     = (const float*)d_in[5];
    const float* W1     = (const float*)d_in[6];
    const float* b1     = (const float*)d_in[7];
    const float* w_ih   = (const float*)d_in[8];
    const float* b_ih   = (const float*)d_in[9];
    const float* w_hh   = (const float*)d_in[10];
    const float* b_hh   = (const float*)d_in[11];
    const float* mlp_w1 = (const float*)d_in[12];
    const float* mlp_b1 = (const float*)d_in[13];
    const float* alpha1 = (const float*)d_in[14];
    const float* bn1g   = (const float*)d_in[15];
    const float* bn1b   = (const float*)d_in[16];
    const float* bn1m   = (const float*)d_in[17];
    const float* bn1v   = (const float*)d_in[18];
    const float* mlp_w2 = (const float*)d_in[19];
    const float* mlp_b2 = (const float*)d_in[20];
    const float* alpha2 = (const float*)d_in[21];
    const float* bn2g   = (const float*)d_in[22];
    const float* bn2b   = (const float*)d_in[23];
    const float* bn2m   = (const float*)d_in[24];
    const float* bn2v   = (const float*)d_in[25];
    const float* w_out  = (const float*)d_in[26];
    const float* b_out  = (const float*)d_in[27];

    float* out = (float*)d_out;
    float* ws = (float*)d_ws;

    // workspace layout (float offsets)
    float* v0   = ws;                  // 4097*64 = 262208
    float* u    = ws + 262208;         // 262208
    float* h1y  = ws + 524416;         // 4096*64 = 262144
    float* part = ws + 786560;         // 8*16*32768 = 4194304
    float* nh   = ws + 4980864;        // 8192
    float* m1s  = ws + 4989056;        // 8192
    float* dis  = ws + 4997248;        // 4096
    float* sm   = ws + 5001344;        // 16
    int* wsi       = (int*)(ws + 5001360);
    int* cnt       = wsi;                       // 4096
    int* row_start = wsi + 4096;                // 4097
    int* cursor    = wsi + 4096 + 4097;         // 4096
    int* csr       = wsi + 4096 + 4097 + 4096;  // PADMAX

    const int* srcp = ei;
    const int* dstp = ei + EE;

    k_init<<<PADMAX / 256, 256, 0, stream>>>(csr, cnt);
    k_hist<<<EE / 256, 256, 0, stream>>>(dstp, cnt);
    k_scan<<<1, 1024, 0, stream>>>(cnt, row_start, cursor, dis, W0, b0, W1, b1, w_out, sm);
    k_fill<<<EE / 256, 256, 0, stream>>>(srcp, dstp, cursor, csr);
    k_v0<<<1025, 256, 0, stream>>>(pos, dis, v0);
    k_gath1<<<1025, 256, 0, stream>>>(v0, row_start, csr, dis, sm, u);
    k_gath2<<<1024, 256, 0, stream>>>(u, row_start, csr, dis, sm, h1y);
    k_gru<<<128, 256, 0, stream>>>(x, hidden, w_ih, b_ih, w_hh, b_hh, out + BB * NN * 3, nh);
    k_mlp1<<<128, 256, 0, stream>>>(nh, mlp_w1, mlp_b1, alpha1, bn1g, bn1b, bn1m, bn1v, m1s);
    k_mlp2<<<512, 256, 0, stream>>>(m1s, mlp_w2, part);
    k_out<<<(BB * NN) / 256, 256, 0, stream>>>(part, h1y, mlp_b2, alpha2, bn2g, bn2b, bn2m,
                                               bn2v, w_out, b_out, out);
}

// Round 10
// 76.141 us; speedup vs baseline: 2.2476x; 1.2257x over previous
//
#include <hip/hip_runtime.h>
#include <math.h>

#define BB 16
#define NN 4096
#define EE 65536
#define IN_F 128
#define HH 512
#define D1 512
#define D2 32768
#define EPSV 1e-5f
#define PADMAX 94208        // EE + NN*7 worst-case padded CSR
#define INIT_BLOCKS 368     // PADMAX/256

// ---------------- stage1: csr-sentinel + cnt init (blocks 0..367)  ||  GRU (blocks 368..495) ----------------

__global__ void k_stage1(int* __restrict__ csr, int* __restrict__ cnt,
                         const float* __restrict__ x, const float* __restrict__ hidden,
                         const float* __restrict__ w_ih, const float* __restrict__ b_ih,
                         const float* __restrict__ w_hh, const float* __restrict__ b_hh,
                         float* __restrict__ nh_out, float* __restrict__ nh_ws) {
    __shared__ float s_x[128];
    __shared__ float s_h[512];
    __shared__ float s_p[4 * 64 * 7];
    int bid = blockIdx.x;
    int tid = threadIdx.x;
    if (bid < INIT_BLOCKS) {
        int i = bid * 256 + tid;
        csr[i] = NN;  // sentinel -> zero feature block
        if (i < 4096) cnt[i] = 0;
        return;
    }
    int gb = bid - INIT_BLOCKS;  // 0..127
    int b = gb >> 3;
    int jblk = gb & 7;
    if (tid < 128) s_x[tid] = x[b * IN_F + tid];
    for (int i = tid; i < 512; i += 256) s_h[i] = hidden[b * HH + i];
    __syncthreads();
    int jloc = tid & 63;
    int ks = tid >> 6;  // 0..3
    int j = jblk * 64 + jloc;
    float air = 0.f, aiz = 0.f, ain = 0.f, ahr = 0.f, ahz = 0.f, ahn = 0.f;
    {
        const float4* wi0 = (const float4*)(w_ih + (size_t)j * IN_F + ks * 32);
        const float4* wi1 = (const float4*)(w_ih + (size_t)(HH + j) * IN_F + ks * 32);
        const float4* wi2 = (const float4*)(w_ih + (size_t)(2 * HH + j) * IN_F + ks * 32);
        const float4* xs = (const float4*)(s_x + ks * 32);
#pragma unroll
        for (int i = 0; i < 8; ++i) {
            float4 xv = xs[i];
            float4 a = wi0[i], c = wi1[i], d = wi2[i];
            air += xv.x * a.x + xv.y * a.y + xv.z * a.z + xv.w * a.w;
            aiz += xv.x * c.x + xv.y * c.y + xv.z * c.z + xv.w * c.w;
            ain += xv.x * d.x + xv.y * d.y + xv.z * d.z + xv.w * d.w;
        }
    }
    {
        const float4* wh0 = (const float4*)(w_hh + (size_t)j * HH + ks * 128);
        const float4* wh1 = (const float4*)(w_hh + (size_t)(HH + j) * HH + ks * 128);
        const float4* wh2 = (const float4*)(w_hh + (size_t)(2 * HH + j) * HH + ks * 128);
        const float4* hs = (const float4*)(s_h + ks * 128);
#pragma unroll 8
        for (int i = 0; i < 32; ++i) {
            float4 hv = hs[i];
            float4 a = wh0[i], c = wh1[i], d = wh2[i];
            ahr += hv.x * a.x + hv.y * a.y + hv.z * a.z + hv.w * a.w;
            ahz += hv.x * c.x + hv.y * c.y + hv.z * c.z + hv.w * c.w;
            ahn += hv.x * d.x + hv.y * d.y + hv.z * d.z + hv.w * d.w;
        }
    }
    float* pp = s_p + (ks * 64 + jloc) * 7;
    pp[0] = air; pp[1] = aiz; pp[2] = ain; pp[3] = ahr; pp[4] = ahz; pp[5] = ahn;
    __syncthreads();
    if (tid < 64) {
        int jj = jblk * 64 + tid;
        float v0 = 0.f, v1 = 0.f, v2 = 0.f, v3 = 0.f, v4 = 0.f, v5 = 0.f;
#pragma unroll
        for (int s = 0; s < 4; ++s) {
            const float* q = s_p + (s * 64 + tid) * 7;
            v0 += q[0]; v1 += q[1]; v2 += q[2]; v3 += q[3]; v4 += q[4]; v5 += q[5];
        }
        float ir = v0 + b_ih[jj], iz = v1 + b_ih[HH + jj], inn = v2 + b_ih[2 * HH + jj];
        float hr = v3 + b_hh[jj], hz = v4 + b_hh[HH + jj], hn = v5 + b_hh[2 * HH + jj];
        float r = 1.f / (1.f + expf(-(ir + hr)));
        float z = 1.f / (1.f + expf(-(iz + hz)));
        float nn = tanhf(inn + r * hn);
        float hprev = s_h[jj];
        float nh = (1.f - z) * nn + z * hprev;
        nh_out[b * HH + jj] = nh;
        nh_ws[b * HH + jj] = nh;
    }
}

// ---------------- stage2: histogram (blocks 0..255)  ||  MLP1 (blocks 256..383) ----------------

__global__ void k_stage2(const int* __restrict__ dst, int* __restrict__ cnt,
                         const float* __restrict__ nh, const float* __restrict__ w1,
                         const float* __restrict__ b1v, const float* __restrict__ alpha1,
                         const float* __restrict__ g1, const float* __restrict__ bt1,
                         const float* __restrict__ mu1, const float* __restrict__ var1,
                         float* __restrict__ m1) {
    __shared__ float s_nh[512];
    __shared__ float s_p[4 * 64];
    int bid = blockIdx.x;
    int tid = threadIdx.x;
    if (bid < 256) {
        int i = bid * 256 + tid;
        atomicAdd(&cnt[dst[i]], 1);
        return;
    }
    int mb = bid - 256;  // 0..127
    int b = mb >> 3;
    int jblk = mb & 7;
    for (int i = tid; i < 512; i += 256) s_nh[i] = nh[b * HH + i];
    __syncthreads();
    int jloc = tid & 63;
    int ks = tid >> 6;
    int j = jblk * 64 + jloc;
    const float* wp = w1 + (size_t)(ks * 128) * D1 + j;
    float acc = 0.f;
#pragma unroll 4
    for (int k0 = 0; k0 < 128; k0 += 4) {
        float w0 = wp[0], w1v = wp[D1], w2v = wp[2 * D1], w3v = wp[3 * D1];
        float4 mv = *(const float4*)&s_nh[ks * 128 + k0];
        acc += mv.x * w0 + mv.y * w1v + mv.z * w2v + mv.w * w3v;
        wp += 4 * D1;
    }
    s_p[ks * 64 + jloc] = acc;
    __syncthreads();
    if (tid < 64) {
        int jj = jblk * 64 + tid;
        float v = s_p[tid] + s_p[64 + tid] + s_p[128 + tid] + s_p[192 + tid];
        v += b1v[jj];
        float al = alpha1[jj];
        v = v > 0.f ? v : al * v;
        float iv = rsqrtf(var1[jj] + EPSV);
        m1[b * D1 + jj] = g1[jj] * (v - mu1[jj]) * iv + bt1[jj];
    }
}

// ---------------- stage3: scan+precompute (block 0)  ||  MLP2 (blocks 1..512) ----------------
// scan: 256 threads, 16 cnt values each; padded prefix; dis; collapsed 3x3 matrices.
// sm layout: [0..8] W0M3 (3x3 row-major k*3+c), [9..11] b0@M3, [12..14] b1@Wh

__global__ void k_stage3(const int* __restrict__ cnt, int* __restrict__ row_start,
                         int* __restrict__ cursor, float* __restrict__ dis,
                         const float* __restrict__ W0, const float* __restrict__ b0,
                         const float* __restrict__ W1, const float* __restrict__ b1,
                         const float* __restrict__ w_out, float* __restrict__ sm,
                         const float* __restrict__ m1, const float* __restrict__ w2,
                         float* __restrict__ part) {
    __shared__ float s_m1[16 * 64];
    __shared__ int lds[256];
    __shared__ float sm3[192];
    int bid = blockIdx.x;
    int tid = threadIdx.x;
    if (bid == 0) {
        int base = tid * 16;
        int v[16], p[16];
        int tot = 0;
#pragma unroll
        for (int i = 0; i < 16; ++i) {
            v[i] = cnt[base + i];
            p[i] = (v[i] + 7) & ~7;
            tot += p[i];
        }
        lds[tid] = tot;
        __syncthreads();
        for (int off = 1; off < 256; off <<= 1) {
            int t = (tid >= off) ? lds[tid - off] : 0;
            __syncthreads();
            lds[tid] += t;
            __syncthreads();
        }
        int e = (tid > 0) ? lds[tid - 1] : 0;
#pragma unroll
        for (int i = 0; i < 16; ++i) {
            row_start[base + i] = e;
            cursor[base + i] = e;
            dis[base + i] = rsqrtf((float)(v[i] + 1));
            e += p[i];
        }
        if (tid == 255) row_start[4096] = lds[255];
        // small matrices: M3 = W1 @ w_out[8:72] (64x3), then 3x3 collapse
        if (tid < 192) {
            int f = tid / 3, c = tid - 3 * (tid / 3);
            float acc = 0.f;
            for (int g = 0; g < 64; ++g) acc += W1[f * 64 + g] * w_out[(8 + g) * 3 + c];
            sm3[tid] = acc;
        }
        __syncthreads();
        if (tid < 9) {
            int k = tid / 3, c = tid - 3 * (tid / 3);
            float acc = 0.f;
            for (int f = 0; f < 64; ++f) acc += W0[k * 64 + f] * sm3[f * 3 + c];
            sm[tid] = acc;
        } else if (tid < 12) {
            int c = tid - 9;
            float acc = 0.f;
            for (int f = 0; f < 64; ++f) acc += b0[f] * sm3[f * 3 + c];
            sm[tid] = acc;
        } else if (tid < 15) {
            int c = tid - 12;
            float acc = 0.f;
            for (int g = 0; g < 64; ++g) acc += b1[g] * w_out[(8 + g) * 3 + c];
            sm[tid] = acc;
        }
        return;
    }
    int mb = bid - 1;  // 0..511
    int jt = mb >> 3;
    int ok = mb & 7;
    {
        int b = tid >> 4, kg = tid & 15;
        *(float4*)&s_m1[b * 64 + kg * 4] = *(const float4*)(m1 + b * 512 + ok * 64 + kg * 4);
    }
    __syncthreads();
    int j = jt * 512 + tid * 2;
    const float* wp = w2 + (size_t)(ok * 64) * D2 + j;
    float2 wb0 = *(const float2*)(wp + 0 * (size_t)D2);
    float2 wb1 = *(const float2*)(wp + 1 * (size_t)D2);
    float2 wb2 = *(const float2*)(wp + 2 * (size_t)D2);
    float2 wb3 = *(const float2*)(wp + 3 * (size_t)D2);
    float acc0[16], acc1[16];
#pragma unroll
    for (int b = 0; b < 16; ++b) { acc0[b] = 0.f; acc1[b] = 0.f; }
    for (int k4 = 0; k4 < 64; k4 += 4) {
        float2 c0 = wb0, c1 = wb1, c2 = wb2, c3 = wb3;
        int kp = (k4 + 4 < 64) ? k4 + 4 : 0;
        wb0 = *(const float2*)(wp + (size_t)(kp + 0) * D2);
        wb1 = *(const float2*)(wp + (size_t)(kp + 1) * D2);
        wb2 = *(const float2*)(wp + (size_t)(kp + 2) * D2);
        wb3 = *(const float2*)(wp + (size_t)(kp + 3) * D2);
#pragma unroll
        for (int b = 0; b < 16; ++b) {
            float2 p01 = *(const float2*)&s_m1[b * 64 + k4];
            float2 p23 = *(const float2*)&s_m1[b * 64 + k4 + 2];
            acc0[b] += p01.x * c0.x + p01.y * c1.x + p23.x * c2.x + p23.y * c3.x;
            acc1[b] += p01.x * c0.y + p01.y * c1.y + p23.x * c2.y + p23.y * c3.y;
        }
    }
    float* pb = part + (size_t)(ok * 16) * D2 + j;
#pragma unroll
    for (int b = 0; b < 16; ++b) {
        *(float2*)(pb + (size_t)b * D2) = make_float2(acc0[b], acc1[b]);
    }
}

// ---------------- stage4: CSR fill (blocks 0..255)  ||  v0 build (blocks 256..1280) ----------------

__global__ void k_stage4(const int* __restrict__ src, const int* __restrict__ dst,
                         int* __restrict__ cursor, int* __restrict__ csr_src,
                         const float* __restrict__ pos, const float* __restrict__ dis,
                         float* __restrict__ v0) {
    int bid = blockIdx.x;
    int tid = threadIdx.x;
    if (bid < 256) {
        int i = bid * 256 + tid;
        int d = dst[i];
        int p = atomicAdd(&cursor[d], 1);
        csr_src[p] = src[i];
        return;
    }
    int vb = bid - 256;  // 0..1024
    int n = vb * 4 + (tid >> 6);
    int l = tid & 63;
    if (n > NN) return;
    if (n == NN) { v0[(size_t)NN * 64 + l] = 0.f; return; }
    int b = l >> 2, c = l & 3;
    float val = 0.f;
    if (c < 3) val = dis[n] * pos[(size_t)b * (NN * 3) + n * 3 + c];
    v0[(size_t)n * 64 + l] = val;
}

// ---------------- gather pass 1: P = v0[n] + sum_in v0[s]; u = dis^2*(P@W0M3)+dis*b0M3 ----------------

__global__ __launch_bounds__(256) void k_gath1(const float* __restrict__ v0,
                                               const int* __restrict__ row_start,
                                               const int* __restrict__ csr,
                                               const float* __restrict__ dis,
                                               const float* __restrict__ sm,
                                               float* __restrict__ u) {
    __shared__ int sidx[4][128];
    __shared__ float sP[4][64];
    int w = threadIdx.x >> 6;
    int l = threadIdx.x & 63;
    int n = blockIdx.x * 4 + w;
    if (n > NN) return;
    if (n == NN) { u[(size_t)NN * 64 + l] = 0.f; return; }
    int rs = row_start[n];
    int deg = row_start[n + 1] - rs;  // multiple of 8
    if (l < deg) sidx[w][l] = csr[rs + l];
    if (64 + l < deg && 64 + l < 128) sidx[w][64 + l] = csr[rs + 64 + l];
    float acc = v0[(size_t)n * 64 + l];
    int degc = deg < 128 ? deg : 128;
    int nch = degc >> 3;
    float A[8], B[8];
    if (nch > 0) {
#pragma unroll
        for (int i = 0; i < 8; ++i) A[i] = v0[(size_t)sidx[w][i] * 64 + l];
    }
    for (int c = 0; c < nch; ++c) {
        if (c + 1 < nch) {
            int base = (c + 1) * 8;
#pragma unroll
            for (int i = 0; i < 8; ++i) B[i] = v0[(size_t)sidx[w][base + i] * 64 + l];
        }
#pragma unroll
        for (int i = 0; i < 8; ++i) acc += A[i];
        if (c + 1 < nch) {
#pragma unroll
            for (int i = 0; i < 8; ++i) A[i] = B[i];
        }
    }
    for (int e = 128; e < deg; ++e) acc += v0[(size_t)csr[rs + e] * 64 + l];
    sP[w][l] = acc;
    int base = l & ~3;
    float P0 = sP[w][base + 0], P1 = sP[w][base + 1], P2 = sP[w][base + 2];
    int c = l & 3;
    float d = dis[n];
    float uu = 0.f;
    if (c < 3)
        uu = d * d * (P0 * sm[c] + P1 * sm[3 + c] + P2 * sm[6 + c]) + d * sm[9 + c];
    u[(size_t)n * 64 + l] = uu;
}

// ---------------- gather pass 2: h1y = dis[n]*(u[n]+sum_in u[s]) + b1Wh ----------------

__global__ __launch_bounds__(256) void k_gath2(const float* __restrict__ u,
                                               const int* __restrict__ row_start,
                                               const int* __restrict__ csr,
                                               const float* __restrict__ dis,
                                               const float* __restrict__ sm,
                                               float* __restrict__ h1y) {
    __shared__ int sidx[4][128];
    int w = threadIdx.x >> 6;
    int l = threadIdx.x & 63;
    int n = blockIdx.x * 4 + w;
    if (n >= NN) return;
    int rs = row_start[n];
    int deg = row_start[n + 1] - rs;
    if (l < deg) sidx[w][l] = csr[rs + l];
    if (64 + l < deg && 64 + l < 128) sidx[w][64 + l] = csr[rs + 64 + l];
    float acc = u[(size_t)n * 64 + l];
    int degc = deg < 128 ? deg : 128;
    int nch = degc >> 3;
    float A[8], B[8];
    if (nch > 0) {
#pragma unroll
        for (int i = 0; i < 8; ++i) A[i] = u[(size_t)sidx[w][i] * 64 + l];
    }
    for (int c = 0; c < nch; ++c) {
        if (c + 1 < nch) {
            int base = (c + 1) * 8;
#pragma unroll
            for (int i = 0; i < 8; ++i) B[i] = u[(size_t)sidx[w][base + i] * 64 + l];
        }
#pragma unroll
        for (int i = 0; i < 8; ++i) acc += A[i];
        if (c + 1 < nch) {
#pragma unroll
            for (int i = 0; i < 8; ++i) A[i] = B[i];
        }
    }
    for (int e = 128; e < deg; ++e) acc += u[(size_t)csr[rs + e] * 64 + l];
    int c = l & 3;
    float val = dis[n] * acc + ((c < 3) ? sm[12 + c] : 0.f);
    h1y[(size_t)n * 64 + l] = val;
}

// ---------------- Output head: mlp2-reduce + bias/PReLU/BN + gru@w_out + h1y ----------------

__global__ void k_out(const float* __restrict__ part, const float* __restrict__ h1y,
                      const float* __restrict__ b2, const float* __restrict__ alpha2,
                      const float* __restrict__ g2, const float* __restrict__ bt2,
                      const float* __restrict__ mu2, const float* __restrict__ var2,
                      const float* __restrict__ w_out, const float* __restrict__ b_out,
                      float* __restrict__ y) {
    __shared__ float sw[24];
    __shared__ float sb[3];
    int tid = threadIdx.x;
    if (tid < 24) sw[tid] = w_out[tid];
    if (tid < 3) sb[tid] = b_out[tid];
    __syncthreads();
    int t = blockIdx.x * 256 + tid;
    int n = t & (NN - 1);
    int b = t >> 12;
    int j0 = n * 8;
    float4 sA = make_float4(0.f, 0.f, 0.f, 0.f);
    float4 sB = make_float4(0.f, 0.f, 0.f, 0.f);
#pragma unroll
    for (int ok = 0; ok < 8; ++ok) {
        const float* pp = part + (size_t)(ok * 16 + b) * D2 + j0;
        float4 pa = *(const float4*)pp;
        float4 pb = *(const float4*)(pp + 4);
        sA.x += pa.x; sA.y += pa.y; sA.z += pa.z; sA.w += pa.w;
        sB.x += pb.x; sB.y += pb.y; sB.z += pb.z; sB.w += pb.w;
    }
    float raw[8] = {sA.x, sA.y, sA.z, sA.w, sB.x, sB.y, sB.z, sB.w};
    float4 bja = *(const float4*)(b2 + j0),    bjb = *(const float4*)(b2 + j0 + 4);
    float4 ala = *(const float4*)(alpha2 + j0), alb = *(const float4*)(alpha2 + j0 + 4);
    float4 gaa = *(const float4*)(g2 + j0),    gab = *(const float4*)(g2 + j0 + 4);
    float4 bea = *(const float4*)(bt2 + j0),   beb = *(const float4*)(bt2 + j0 + 4);
    float4 mua = *(const float4*)(mu2 + j0),   mub = *(const float4*)(mu2 + j0 + 4);
    float4 vaa = *(const float4*)(var2 + j0),  vab = *(const float4*)(var2 + j0 + 4);
    float bj[8] = {bja.x, bja.y, bja.z, bja.w, bjb.x, bjb.y, bjb.z, bjb.w};
    float al[8] = {ala.x, ala.y, ala.z, ala.w, alb.x, alb.y, alb.z, alb.w};
    float ga[8] = {gaa.x, gaa.y, gaa.z, gaa.w, gab.x, gab.y, gab.z, gab.w};
    float be[8] = {bea.x, bea.y, bea.z, bea.w, beb.x, beb.y, beb.z, beb.w};
    float mu[8] = {mua.x, mua.y, mua.z, mua.w, mub.x, mub.y, mub.z, mub.w};
    float va[8] = {vaa.x, vaa.y, vaa.z, vaa.w, vab.x, vab.y, vab.z, vab.w};
    float4 hv = *(const float4*)(h1y + (size_t)n * 64 + b * 4);
    float y0 = sb[0] + hv.x, y1 = sb[1] + hv.y, y2 = sb[2] + hv.z;
#pragma unroll
    for (int g = 0; g < 8; ++g) {
        float v = raw[g] + bj[g];
        v = v > 0.f ? v : al[g] * v;
        v = ga[g] * (v - mu[g]) * rsqrtf(va[g] + EPSV) + be[g];
        y0 += v * sw[g * 3 + 0];
        y1 += v * sw[g * 3 + 1];
        y2 += v * sw[g * 3 + 2];
    }
    float* yo = y + (size_t)b * (NN * 3) + n * 3;
    yo[0] = y0;
    yo[1] = y1;
    yo[2] = y2;
}

// ---------------- launcher ----------------

extern "C" void kernel_launch(void* const* d_in, const int* in_sizes, int n_in,
                              void* d_out, int out_size, void* d_ws, size_t ws_size,
                              hipStream_t stream) {
    const float* x      = (const float*)d_in[0];
    const float* pos    = (const float*)d_in[1];
    const float* hidden = (const float*)d_in[2];
    const int*   ei     = (const int*)d_in[3];
    const float* W0     = (const float*)d_in[4];
    const float* b0     = (const float*)d_in[5];
    const float* W1     = (const float*)d_in[6];
    const float* b1     = (const float*)d_in[7];
    const float* w_ih   = (const float*)d_in[8];
    const float* b_ih   = (const float*)d_in[9];
    const float* w_hh   = (const float*)d_in[10];
    const float* b_hh   = (const float*)d_in[11];
    const float* mlp_w1 = (const float*)d_in[12];
    const float* mlp_b1 = (const float*)d_in[13];
    const float* alpha1 = (const float*)d_in[14];
    const float* bn1g   = (const float*)d_in[15];
    const float* bn1b   = (const float*)d_in[16];
    const float* bn1m   = (const float*)d_in[17];
    const float* bn1v   = (const float*)d_in[18];
    const float* mlp_w2 = (const float*)d_in[19];
    const float* mlp_b2 = (const float*)d_in[20];
    const float* alpha2 = (const float*)d_in[21];
    const float* bn2g   = (const float*)d_in[22];
    const float* bn2b   = (const float*)d_in[23];
    const float* bn2m   = (const float*)d_in[24];
    const float* bn2v   = (const float*)d_in[25];
    const float* w_out  = (const float*)d_in[26];
    const float* b_out  = (const float*)d_in[27];

    float* out = (float*)d_out;
    float* ws = (float*)d_ws;

    // workspace layout (float offsets)
    float* v0   = ws;                  // 4097*64 = 262208
    float* u    = ws + 262208;         // 262208
    float* h1y  = ws + 524416;         // 4096*64 = 262144
    float* part = ws + 786560;         // 8*16*32768 = 4194304
    float* nh   = ws + 4980864;        // 8192
    float* m1s  = ws + 4989056;        // 8192
    float* dis  = ws + 4997248;        // 4096
    float* sm   = ws + 5001344;        // 16
    int* wsi       = (int*)(ws + 5001360);
    int* cnt       = wsi;                       // 4096
    int* row_start = wsi + 4096;                // 4097
    int* cursor    = wsi + 4096 + 4097;         // 4096
    int* csr       = wsi + 4096 + 4097 + 4096;  // PADMAX

    const int* srcp = ei;
    const int* dstp = ei + EE;

    k_stage1<<<INIT_BLOCKS + 128, 256, 0, stream>>>(csr, cnt, x, hidden, w_ih, b_ih, w_hh,
                                                    b_hh, out + BB * NN * 3, nh);
    k_stage2<<<256 + 128, 256, 0, stream>>>(dstp, cnt, nh, mlp_w1, mlp_b1, alpha1, bn1g,
                                            bn1b, bn1m, bn1v, m1s);
    k_stage3<<<1 + 512, 256, 0, stream>>>(cnt, row_start, cursor, dis, W0, b0, W1, b1,
                                          w_out, sm, m1s, mlp_w2, part);
    k_stage4<<<256 + 1025, 256, 0, stream>>>(srcp, dstp, cursor, csr, pos, dis, v0);
    k_gath1<<<1025, 256, 0, stream>>>(v0, row_start, csr, dis, sm, u);
    k_gath2<<<1024, 256, 0, stream>>>(u, row_start, csr, dis, sm, h1y);
    k_out<<<(BB * NN) / 256, 256, 0, stream>>>(part, h1y, mlp_b2, alpha2, bn2g, bn2b, bn2m,
                                               bn2v, w_out, b_out, out);
}

// Round 11
// 75.375 us; speedup vs baseline: 2.2704x; 1.0102x over previous
//
#include <hip/hip_runtime.h>
#include <math.h>

#define BB 16
#define NN 4096
#define EE 65536
#define IN_F 128
#define HH 512
#define D1 512
#define D2 32768
#define EPSV 1e-5f
#define PADMAX 94208        // EE + NN*7 worst-case padded CSR
#define INIT_BLOCKS 368     // PADMAX/256

// ---------------- stage1: csr-sentinel + cnt init (blocks 0..367)  ||  GRU (blocks 368..623) ----------------
// GRU: 256 blocks = 16 b x 16 jblk(32 cols); thread = (jloc 0..31, ks 0..7)

__global__ void k_stage1(int* __restrict__ csr, int* __restrict__ cnt,
                         const float* __restrict__ x, const float* __restrict__ hidden,
                         const float* __restrict__ w_ih, const float* __restrict__ b_ih,
                         const float* __restrict__ w_hh, const float* __restrict__ b_hh,
                         float* __restrict__ nh_out, float* __restrict__ nh_ws) {
    __shared__ float s_x[128];
    __shared__ float s_h[512];
    __shared__ float s_p[8 * 32 * 7];
    int bid = blockIdx.x;
    int tid = threadIdx.x;
    if (bid < INIT_BLOCKS) {
        int i = bid * 256 + tid;
        csr[i] = NN;  // sentinel -> zero feature block
        if (i < 4096) cnt[i] = 0;
        return;
    }
    int gb = bid - INIT_BLOCKS;  // 0..255
    int b = gb >> 4;
    int jblk = gb & 15;
    if (tid < 128) s_x[tid] = x[b * IN_F + tid];
    for (int i = tid; i < 512; i += 256) s_h[i] = hidden[b * HH + i];
    __syncthreads();
    int jloc = tid & 31;
    int ks = tid >> 5;  // 0..7
    int j = jblk * 32 + jloc;
    float air = 0.f, aiz = 0.f, ain = 0.f, ahr = 0.f, ahz = 0.f, ahn = 0.f;
    {
        const float4* wi0 = (const float4*)(w_ih + (size_t)j * IN_F + ks * 16);
        const float4* wi1 = (const float4*)(w_ih + (size_t)(HH + j) * IN_F + ks * 16);
        const float4* wi2 = (const float4*)(w_ih + (size_t)(2 * HH + j) * IN_F + ks * 16);
        const float4* xs = (const float4*)(s_x + ks * 16);
#pragma unroll
        for (int i = 0; i < 4; ++i) {
            float4 xv = xs[i];
            float4 a = wi0[i], c = wi1[i], d = wi2[i];
            air += xv.x * a.x + xv.y * a.y + xv.z * a.z + xv.w * a.w;
            aiz += xv.x * c.x + xv.y * c.y + xv.z * c.z + xv.w * c.w;
            ain += xv.x * d.x + xv.y * d.y + xv.z * d.z + xv.w * d.w;
        }
    }
    {
        const float4* wh0 = (const float4*)(w_hh + (size_t)j * HH + ks * 64);
        const float4* wh1 = (const float4*)(w_hh + (size_t)(HH + j) * HH + ks * 64);
        const float4* wh2 = (const float4*)(w_hh + (size_t)(2 * HH + j) * HH + ks * 64);
        const float4* hs = (const float4*)(s_h + ks * 64);
#pragma unroll 8
        for (int i = 0; i < 16; ++i) {
            float4 hv = hs[i];
            float4 a = wh0[i], c = wh1[i], d = wh2[i];
            ahr += hv.x * a.x + hv.y * a.y + hv.z * a.z + hv.w * a.w;
            ahz += hv.x * c.x + hv.y * c.y + hv.z * c.z + hv.w * c.w;
            ahn += hv.x * d.x + hv.y * d.y + hv.z * d.z + hv.w * d.w;
        }
    }
    float* pp = s_p + (ks * 32 + jloc) * 7;
    pp[0] = air; pp[1] = aiz; pp[2] = ain; pp[3] = ahr; pp[4] = ahz; pp[5] = ahn;
    __syncthreads();
    if (tid < 32) {
        int jj = jblk * 32 + tid;
        float v0 = 0.f, v1 = 0.f, v2 = 0.f, v3 = 0.f, v4 = 0.f, v5 = 0.f;
#pragma unroll
        for (int s = 0; s < 8; ++s) {
            const float* q = s_p + (s * 32 + tid) * 7;
            v0 += q[0]; v1 += q[1]; v2 += q[2]; v3 += q[3]; v4 += q[4]; v5 += q[5];
        }
        float ir = v0 + b_ih[jj], iz = v1 + b_ih[HH + jj], inn = v2 + b_ih[2 * HH + jj];
        float hr = v3 + b_hh[jj], hz = v4 + b_hh[HH + jj], hn = v5 + b_hh[2 * HH + jj];
        float r = 1.f / (1.f + expf(-(ir + hr)));
        float z = 1.f / (1.f + expf(-(iz + hz)));
        float nn = tanhf(inn + r * hn);
        float hprev = s_h[jj];
        float nh = (1.f - z) * nn + z * hprev;
        nh_out[b * HH + jj] = nh;
        nh_ws[b * HH + jj] = nh;
    }
}

// ---------------- stage2: histogram (blocks 0..255)  ||  MLP1 (blocks 256..383) ----------------

__global__ void k_stage2(const int* __restrict__ dst, int* __restrict__ cnt,
                         const float* __restrict__ nh, const float* __restrict__ w1,
                         const float* __restrict__ b1v, const float* __restrict__ alpha1,
                         const float* __restrict__ g1, const float* __restrict__ bt1,
                         const float* __restrict__ mu1, const float* __restrict__ var1,
                         float* __restrict__ m1) {
    __shared__ float s_nh[512];
    __shared__ float s_p[4 * 64];
    int bid = blockIdx.x;
    int tid = threadIdx.x;
    if (bid < 256) {
        int i = bid * 256 + tid;
        atomicAdd(&cnt[dst[i]], 1);
        return;
    }
    int mb = bid - 256;  // 0..127
    int b = mb >> 3;
    int jblk = mb & 7;
    for (int i = tid; i < 512; i += 256) s_nh[i] = nh[b * HH + i];
    __syncthreads();
    int jloc = tid & 63;
    int ks = tid >> 6;
    int j = jblk * 64 + jloc;
    const float* wp = w1 + (size_t)(ks * 128) * D1 + j;
    float acc = 0.f;
#pragma unroll 4
    for (int k0 = 0; k0 < 128; k0 += 4) {
        float w0 = wp[0], w1v = wp[D1], w2v = wp[2 * D1], w3v = wp[3 * D1];
        float4 mv = *(const float4*)&s_nh[ks * 128 + k0];
        acc += mv.x * w0 + mv.y * w1v + mv.z * w2v + mv.w * w3v;
        wp += 4 * D1;
    }
    s_p[ks * 64 + jloc] = acc;
    __syncthreads();
    if (tid < 64) {
        int jj = jblk * 64 + tid;
        float v = s_p[tid] + s_p[64 + tid] + s_p[128 + tid] + s_p[192 + tid];
        v += b1v[jj];
        float al = alpha1[jj];
        v = v > 0.f ? v : al * v;
        float iv = rsqrtf(var1[jj] + EPSV);
        m1[b * D1 + jj] = g1[jj] * (v - mu1[jj]) * iv + bt1[jj];
    }
}

// ---------------- stage3: scan+precompute (block 0)  ||  v0 build (blocks 1..1025) ----------------
// v0 computes its own dis = rsqrt(cnt+1) -- depends only on cnt, not on scan.
// sm layout: [0..8] W0M3 (3x3 row-major k*3+c), [9..11] b0@M3, [12..14] b1@Wh

__global__ void k_stage3(const int* __restrict__ cnt, int* __restrict__ row_start,
                         int* __restrict__ cursor, float* __restrict__ dis,
                         const float* __restrict__ W0, const float* __restrict__ b0,
                         const float* __restrict__ W1, const float* __restrict__ b1,
                         const float* __restrict__ w_out, float* __restrict__ sm,
                         const float* __restrict__ pos, float* __restrict__ v0) {
    __shared__ int lds[256];
    __shared__ float sm3[192];
    int bid = blockIdx.x;
    int tid = threadIdx.x;
    if (bid == 0) {
        int base = tid * 16;
        int v[16], p[16];
        int tot = 0;
#pragma unroll
        for (int i = 0; i < 16; ++i) {
            v[i] = cnt[base + i];
            p[i] = (v[i] + 7) & ~7;
            tot += p[i];
        }
        lds[tid] = tot;
        __syncthreads();
        for (int off = 1; off < 256; off <<= 1) {
            int t = (tid >= off) ? lds[tid - off] : 0;
            __syncthreads();
            lds[tid] += t;
            __syncthreads();
        }
        int e = (tid > 0) ? lds[tid - 1] : 0;
#pragma unroll
        for (int i = 0; i < 16; ++i) {
            row_start[base + i] = e;
            cursor[base + i] = e;
            dis[base + i] = rsqrtf((float)(v[i] + 1));
            e += p[i];
        }
        if (tid == 255) row_start[4096] = lds[255];
        if (tid < 192) {
            int f = tid / 3, c = tid - 3 * (tid / 3);
            float acc = 0.f;
            for (int g = 0; g < 64; ++g) acc += W1[f * 64 + g] * w_out[(8 + g) * 3 + c];
            sm3[tid] = acc;
        }
        __syncthreads();
        if (tid < 9) {
            int k = tid / 3, c = tid - 3 * (tid / 3);
            float acc = 0.f;
            for (int f = 0; f < 64; ++f) acc += W0[k * 64 + f] * sm3[f * 3 + c];
            sm[tid] = acc;
        } else if (tid < 12) {
            int c = tid - 9;
            float acc = 0.f;
            for (int f = 0; f < 64; ++f) acc += b0[f] * sm3[f * 3 + c];
            sm[tid] = acc;
        } else if (tid < 15) {
            int c = tid - 12;
            float acc = 0.f;
            for (int g = 0; g < 64; ++g) acc += b1[g] * w_out[(8 + g) * 3 + c];
            sm[tid] = acc;
        }
        return;
    }
    int vb = bid - 1;  // 0..1024
    int n = vb * 4 + (tid >> 6);
    int l = tid & 63;
    if (n > NN) return;
    if (n == NN) { v0[(size_t)NN * 64 + l] = 0.f; return; }
    int b = l >> 2, c = l & 3;
    float val = 0.f;
    if (c < 3) {
        float d = rsqrtf((float)(cnt[n] + 1));
        val = d * pos[(size_t)b * (NN * 3) + n * 3 + c];
    }
    v0[(size_t)n * 64 + l] = val;
}

// ---------------- stage4: CSR fill ----------------

__global__ void k_fill(const int* __restrict__ src, const int* __restrict__ dst,
                       int* __restrict__ cursor, int* __restrict__ csr_src) {
    int i = blockIdx.x * 256 + threadIdx.x;
    int d = dst[i];
    int p = atomicAdd(&cursor[d], 1);
    csr_src[p] = src[i];
}

// ---------------- stage5: MLP2 half A, ok 0..3 (blocks 0..255)  ||  gather pass 1 (blocks 256..1280) ----------------

__global__ __launch_bounds__(256) void k_stage5(const float* __restrict__ m1,
                                                const float* __restrict__ w2,
                                                float* __restrict__ part,
                                                const float* __restrict__ v0,
                                                const int* __restrict__ row_start,
                                                const int* __restrict__ csr,
                                                const float* __restrict__ dis,
                                                const float* __restrict__ sm,
                                                float* __restrict__ u) {
    __shared__ float s_m1[16 * 64];
    __shared__ int sidx[4][128];
    __shared__ float sP[4][64];
    int bid = blockIdx.x;
    int tid = threadIdx.x;
    if (bid < 256) {
        int jt = bid >> 2;
        int ok = bid & 3;
        {
            int b = tid >> 4, kg = tid & 15;
            *(float4*)&s_m1[b * 64 + kg * 4] = *(const float4*)(m1 + b * 512 + ok * 64 + kg * 4);
        }
        __syncthreads();
        int j = jt * 512 + tid * 2;
        const float* wp = w2 + (size_t)(ok * 64) * D2 + j;
        float2 wb0 = *(const float2*)(wp + 0 * (size_t)D2);
        float2 wb1 = *(const float2*)(wp + 1 * (size_t)D2);
        float2 wb2 = *(const float2*)(wp + 2 * (size_t)D2);
        float2 wb3 = *(const float2*)(wp + 3 * (size_t)D2);
        float acc0[16], acc1[16];
#pragma unroll
        for (int b = 0; b < 16; ++b) { acc0[b] = 0.f; acc1[b] = 0.f; }
        for (int k4 = 0; k4 < 64; k4 += 4) {
            float2 c0 = wb0, c1 = wb1, c2 = wb2, c3 = wb3;
            int kp = (k4 + 4 < 64) ? k4 + 4 : 0;
            wb0 = *(const float2*)(wp + (size_t)(kp + 0) * D2);
            wb1 = *(const float2*)(wp + (size_t)(kp + 1) * D2);
            wb2 = *(const float2*)(wp + (size_t)(kp + 2) * D2);
            wb3 = *(const float2*)(wp + (size_t)(kp + 3) * D2);
#pragma unroll
            for (int b = 0; b < 16; ++b) {
                float2 p01 = *(const float2*)&s_m1[b * 64 + k4];
                float2 p23 = *(const float2*)&s_m1[b * 64 + k4 + 2];
                acc0[b] += p01.x * c0.x + p01.y * c1.x + p23.x * c2.x + p23.y * c3.x;
                acc1[b] += p01.x * c0.y + p01.y * c1.y + p23.x * c2.y + p23.y * c3.y;
            }
        }
        float* pb = part + (size_t)(ok * 16) * D2 + j;
#pragma unroll
        for (int b = 0; b < 16; ++b) {
            *(float2*)(pb + (size_t)b * D2) = make_float2(acc0[b], acc1[b]);
        }
        return;
    }
    int gb = bid - 256;  // 0..1024
    int w = tid >> 6;
    int l = tid & 63;
    int n = gb * 4 + w;
    if (n > NN) return;
    if (n == NN) { u[(size_t)NN * 64 + l] = 0.f; return; }
    int rs = row_start[n];
    int deg = row_start[n + 1] - rs;  // multiple of 8
    if (l < deg) sidx[w][l] = csr[rs + l];
    if (64 + l < deg && 64 + l < 128) sidx[w][64 + l] = csr[rs + 64 + l];
    float acc = v0[(size_t)n * 64 + l];
    int degc = deg < 128 ? deg : 128;
    int nch = degc >> 3;
    float A[8], B[8];
    if (nch > 0) {
#pragma unroll
        for (int i = 0; i < 8; ++i) A[i] = v0[(size_t)sidx[w][i] * 64 + l];
    }
    for (int c = 0; c < nch; ++c) {
        if (c + 1 < nch) {
            int base = (c + 1) * 8;
#pragma unroll
            for (int i = 0; i < 8; ++i) B[i] = v0[(size_t)sidx[w][base + i] * 64 + l];
        }
#pragma unroll
        for (int i = 0; i < 8; ++i) acc += A[i];
        if (c + 1 < nch) {
#pragma unroll
            for (int i = 0; i < 8; ++i) A[i] = B[i];
        }
    }
    for (int e = 128; e < deg; ++e) acc += v0[(size_t)csr[rs + e] * 64 + l];
    sP[w][l] = acc;
    int base = l & ~3;
    float P0 = sP[w][base + 0], P1 = sP[w][base + 1], P2 = sP[w][base + 2];
    int c = l & 3;
    float d = dis[n];
    float uu = 0.f;
    if (c < 3)
        uu = d * d * (P0 * sm[c] + P1 * sm[3 + c] + P2 * sm[6 + c]) + d * sm[9 + c];
    u[(size_t)n * 64 + l] = uu;
}

// ---------------- stage6: MLP2 half B, ok 4..7 (blocks 0..255)  ||  gather pass 2 (blocks 256..1279) ----------------

__global__ __launch_bounds__(256) void k_stage6(const float* __restrict__ m1,
                                                const float* __restrict__ w2,
                                                float* __restrict__ part,
                                                const float* __restrict__ u,
                                                const int* __restrict__ row_start,
                                                const int* __restrict__ csr,
                                                const float* __restrict__ dis,
                                                const float* __restrict__ sm,
                                                float* __restrict__ h1y) {
    __shared__ float s_m1[16 * 64];
    __shared__ int sidx[4][128];
    int bid = blockIdx.x;
    int tid = threadIdx.x;
    if (bid < 256) {
        int jt = bid >> 2;
        int ok = 4 + (bid & 3);
        {
            int b = tid >> 4, kg = tid & 15;
            *(float4*)&s_m1[b * 64 + kg * 4] = *(const float4*)(m1 + b * 512 + ok * 64 + kg * 4);
        }
        __syncthreads();
        int j = jt * 512 + tid * 2;
        const float* wp = w2 + (size_t)(ok * 64) * D2 + j;
        float2 wb0 = *(const float2*)(wp + 0 * (size_t)D2);
        float2 wb1 = *(const float2*)(wp + 1 * (size_t)D2);
        float2 wb2 = *(const float2*)(wp + 2 * (size_t)D2);
        float2 wb3 = *(const float2*)(wp + 3 * (size_t)D2);
        float acc0[16], acc1[16];
#pragma unroll
        for (int b = 0; b < 16; ++b) { acc0[b] = 0.f; acc1[b] = 0.f; }
        for (int k4 = 0; k4 < 64; k4 += 4) {
            float2 c0 = wb0, c1 = wb1, c2 = wb2, c3 = wb3;
            int kp = (k4 + 4 < 64) ? k4 + 4 : 0;
            wb0 = *(const float2*)(wp + (size_t)(kp + 0) * D2);
            wb1 = *(const float2*)(wp + (size_t)(kp + 1) * D2);
            wb2 = *(const float2*)(wp + (size_t)(kp + 2) * D2);
            wb3 = *(const float2*)(wp + (size_t)(kp + 3) * D2);
#pragma unroll
            for (int b = 0; b < 16; ++b) {
                float2 p01 = *(const float2*)&s_m1[b * 64 + k4];
                float2 p23 = *(const float2*)&s_m1[b * 64 + k4 + 2];
                acc0[b] += p01.x * c0.x + p01.y * c1.x + p23.x * c2.x + p23.y * c3.x;
                acc1[b] += p01.x * c0.y + p01.y * c1.y + p23.x * c2.y + p23.y * c3.y;
            }
        }
        float* pb = part + (size_t)(ok * 16) * D2 + j;
#pragma unroll
        for (int b = 0; b < 16; ++b) {
            *(float2*)(pb + (size_t)b * D2) = make_float2(acc0[b], acc1[b]);
        }
        return;
    }
    int gb = bid - 256;  // 0..1023
    int w = tid >> 6;
    int l = tid & 63;
    int n = gb * 4 + w;
    if (n >= NN) return;
    int rs = row_start[n];
    int deg = row_start[n + 1] - rs;
    if (l < deg) sidx[w][l] = csr[rs + l];
    if (64 + l < deg && 64 + l < 128) sidx[w][64 + l] = csr[rs + 64 + l];
    float acc = u[(size_t)n * 64 + l];
    int degc = deg < 128 ? deg : 128;
    int nch = degc >> 3;
    float A[8], B[8];
    if (nch > 0) {
#pragma unroll
        for (int i = 0; i < 8; ++i) A[i] = u[(size_t)sidx[w][i] * 64 + l];
    }
    for (int c = 0; c < nch; ++c) {
        if (c + 1 < nch) {
            int base = (c + 1) * 8;
#pragma unroll
            for (int i = 0; i < 8; ++i) B[i] = u[(size_t)sidx[w][base + i] * 64 + l];
        }
#pragma unroll
        for (int i = 0; i < 8; ++i) acc += A[i];
        if (c + 1 < nch) {
#pragma unroll
            for (int i = 0; i < 8; ++i) A[i] = B[i];
        }
    }
    for (int e = 128; e < deg; ++e) acc += u[(size_t)csr[rs + e] * 64 + l];
    int c = l & 3;
    float val = dis[n] * acc + ((c < 3) ? sm[12 + c] : 0.f);
    h1y[(size_t)n * 64 + l] = val;
}

// ---------------- Output head: mlp2-reduce + bias/PReLU/BN + gru@w_out + h1y ----------------

__global__ void k_out(const float* __restrict__ part, const float* __restrict__ h1y,
                      const float* __restrict__ b2, const float* __restrict__ alpha2,
                      const float* __restrict__ g2, const float* __restrict__ bt2,
                      const float* __restrict__ mu2, const float* __restrict__ var2,
                      const float* __restrict__ w_out, const float* __restrict__ b_out,
                      float* __restrict__ y) {
    __shared__ float sw[24];
    __shared__ float sb[3];
    int tid = threadIdx.x;
    if (tid < 24) sw[tid] = w_out[tid];
    if (tid < 3) sb[tid] = b_out[tid];
    __syncthreads();
    int t = blockIdx.x * 256 + tid;
    int n = t & (NN - 1);
    int b = t >> 12;
    int j0 = n * 8;
    float4 sA = make_float4(0.f, 0.f, 0.f, 0.f);
    float4 sB = make_float4(0.f, 0.f, 0.f, 0.f);
#pragma unroll
    for (int ok = 0; ok < 8; ++ok) {
        const float* pp = part + (size_t)(ok * 16 + b) * D2 + j0;
        float4 pa = *(const float4*)pp;
        float4 pb = *(const float4*)(pp + 4);
        sA.x += pa.x; sA.y += pa.y; sA.z += pa.z; sA.w += pa.w;
        sB.x += pb.x; sB.y += pb.y; sB.z += pb.z; sB.w += pb.w;
    }
    float raw[8] = {sA.x, sA.y, sA.z, sA.w, sB.x, sB.y, sB.z, sB.w};
    float4 bja = *(const float4*)(b2 + j0),    bjb = *(const float4*)(b2 + j0 + 4);
    float4 ala = *(const float4*)(alpha2 + j0), alb = *(const float4*)(alpha2 + j0 + 4);
    float4 gaa = *(const float4*)(g2 + j0),    gab = *(const float4*)(g2 + j0 + 4);
    float4 bea = *(const float4*)(bt2 + j0),   beb = *(const float4*)(bt2 + j0 + 4);
    float4 mua = *(const float4*)(mu2 + j0),   mub = *(const float4*)(mu2 + j0 + 4);
    float4 vaa = *(const float4*)(var2 + j0),  vab = *(const float4*)(var2 + j0 + 4);
    float bj[8] = {bja.x, bja.y, bja.z, bja.w, bjb.x, bjb.y, bjb.z, bjb.w};
    float al[8] = {ala.x, ala.y, ala.z, ala.w, alb.x, alb.y, alb.z, alb.w};
    float ga[8] = {gaa.x, gaa.y, gaa.z, gaa.w, gab.x, gab.y, gab.z, gab.w};
    float be[8] = {bea.x, bea.y, bea.z, bea.w, beb.x, beb.y, beb.z, beb.w};
    float mu[8] = {mua.x, mua.y, mua.z, mua.w, mub.x, mub.y, mub.z, mub.w};
    float va[8] = {vaa.x, vaa.y, vaa.z, vaa.w, vab.x, vab.y, vab.z, vab.w};
    float4 hv = *(const float4*)(h1y + (size_t)n * 64 + b * 4);
    float y0 = sb[0] + hv.x, y1 = sb[1] + hv.y, y2 = sb[2] + hv.z;
#pragma unroll
    for (int g = 0; g < 8; ++g) {
        float v = raw[g] + bj[g];
        v = v > 0.f ? v : al[g] * v;
        v = ga[g] * (v - mu[g]) * rsqrtf(va[g] + EPSV) + be[g];
        y0 += v * sw[g * 3 + 0];
        y1 += v * sw[g * 3 + 1];
        y2 += v * sw[g * 3 + 2];
    }
    float* yo = y + (size_t)b * (NN * 3) + n * 3;
    yo[0] = y0;
    yo[1] = y1;
    yo[2] = y2;
}

// ---------------- launcher ----------------

extern "C" void kernel_launch(void* const* d_in, const int* in_sizes, int n_in,
                              void* d_out, int out_size, void* d_ws, size_t ws_size,
                              hipStream_t stream) {
    const float* x      = (const float*)d_in[0];
    const float* pos    = (const float*)d_in[1];
    const float* hidden = (const float*)d_in[2];
    const int*   ei     = (const int*)d_in[3];
    const float* W0     = (const float*)d_in[4];
    const float* b0     = (const float*)d_in[5];
    const float* W1     = (const float*)d_in[6];
    const float* b1     = (const float*)d_in[7];
    const float* w_ih   = (const float*)d_in[8];
    const float* b_ih   = (const float*)d_in[9];
    const float* w_hh   = (const float*)d_in[10];
    const float* b_hh   = (const float*)d_in[11];
    const float* mlp_w1 = (const float*)d_in[12];
    const float* mlp_b1 = (const float*)d_in[13];
    const float* alpha1 = (const float*)d_in[14];
    const float* bn1g   = (const float*)d_in[15];
    const float* bn1b   = (const float*)d_in[16];
    const float* bn1m   = (const float*)d_in[17];
    const float* bn1v   = (const float*)d_in[18];
    const float* mlp_w2 = (const float*)d_in[19];
    const float* mlp_b2 = (const float*)d_in[20];
    const float* alpha2 = (const float*)d_in[21];
    const float* bn2g   = (const float*)d_in[22];
    const float* bn2b   = (const float*)d_in[23];
    const float* bn2m   = (const float*)d_in[24];
    const float* bn2v   = (const float*)d_in[25];
    const float* w_out  = (const float*)d_in[26];
    const float* b_out  = (const float*)d_in[27];

    float* out = (float*)d_out;
    float* ws = (float*)d_ws;

    // workspace layout (float offsets)
    float* v0   = ws;                  // 4097*64 = 262208
    float* u    = ws + 262208;         // 262208
    float* h1y  = ws + 524416;         // 4096*64 = 262144
    float* part = ws + 786560;         // 8*16*32768 = 4194304
    float* nh   = ws + 4980864;        // 8192
    float* m1s  = ws + 4989056;        // 8192
    float* dis  = ws + 4997248;        // 4096
    float* sm   = ws + 5001344;        // 16
    int* wsi       = (int*)(ws + 5001360);
    int* cnt       = wsi;                       // 4096
    int* row_start = wsi + 4096;                // 4097
    int* cursor    = wsi + 4096 + 4097;         // 4096
    int* csr       = wsi + 4096 + 4097 + 4096;  // PADMAX

    const int* srcp = ei;
    const int* dstp = ei + EE;

    k_stage1<<<INIT_BLOCKS + 256, 256, 0, stream>>>(csr, cnt, x, hidden, w_ih, b_ih, w_hh,
                                                    b_hh, out + BB * NN * 3, nh);
    k_stage2<<<256 + 128, 256, 0, stream>>>(dstp, cnt, nh, mlp_w1, mlp_b1, alpha1, bn1g,
                                            bn1b, bn1m, bn1v, m1s);
    k_stage3<<<1 + 1025, 256, 0, stream>>>(cnt, row_start, cursor, dis, W0, b0, W1, b1,
                                           w_out, sm, pos, v0);
    k_fill<<<256, 256, 0, stream>>>(srcp, dstp, cursor, csr);
    k_stage5<<<256 + 1025, 256, 0, stream>>>(m1s, mlp_w2, part, v0, row_start, csr, dis,
                                             sm, u);
    k_stage6<<<256 + 1024, 256, 0, stream>>>(m1s, mlp_w2, part, u, row_start, csr, dis,
                                             sm, h1y);
    k_out<<<(BB * NN) / 256, 256, 0, stream>>>(part, h1y, mlp_b2, alpha2, bn2g, bn2b, bn2m,
                                               bn2v, w_out, b_out, out);
}